// Round 1
// baseline (4939.561 us; speedup 1.0000x reference)
//
#include <hip/hip_runtime.h>

#define DEV __device__ __forceinline__

DEV float sigmoidf_(float x) { return 1.f / (1.f + __expf(-x)); }
DEV float siluf_(float x)    { return x * sigmoidf_(x); }
DEV float softplusf_(float x){ return fmaxf(x, 0.f) + log1pf(__expf(-fabsf(x))); }

// ---------------- LayerNorm over C (NCHW in -> NHWC out) ----------------
__global__ __launch_bounds__(256)
void ln_kernel(const float* __restrict__ x, const float* __restrict__ g,
               const float* __restrict__ b, float* __restrict__ xn) {
  const int C = 192, HW = 4096;
  __shared__ float tile[64][193];
  __shared__ float red[2][4][64];
  __shared__ float mean_s[64], rstd_s[64];
  int bb = blockIdx.x >> 6;          // batch (64 tiles per batch)
  int p0 = (blockIdx.x & 63) << 6;   // pixel base
  int tid = threadIdx.x;
  int p = tid & 63, c4 = tid >> 6;
  for (int c = c4; c < C; c += 4)
    tile[p][c] = x[((size_t)(bb * C + c)) * HW + p0 + p];
  __syncthreads();
  float s = 0.f, s2 = 0.f;
  for (int c = c4 * 48; c < c4 * 48 + 48; ++c) { float v = tile[p][c]; s += v; s2 += v * v; }
  red[0][c4][p] = s; red[1][c4][p] = s2;
  __syncthreads();
  if (c4 == 0) {
    float ss = red[0][0][p] + red[0][1][p] + red[0][2][p] + red[0][3][p];
    float qq = red[1][0][p] + red[1][1][p] + red[1][2][p] + red[1][3][p];
    float m = ss * (1.f / 192.f);
    float var = qq * (1.f / 192.f) - m * m;
    mean_s[p] = m;
    rstd_s[p] = rsqrtf(var + 1e-5f);
  }
  __syncthreads();
  for (int e = tid; e < 64 * 192; e += 256) {
    int pp = e / 192, c = e % 192;
    xn[((size_t)bb * HW + p0 + pp) * C + c] =
        (tile[pp][c] - mean_s[pp]) * rstd_s[pp] * g[c] + b[c];
  }
}

// ---------------- Generic fp32 tiled GEMM: C[m,n] = sum_k A[m,k]*B(k,n) + bias[n] ----------------
// TRANSB=false: B element (k,n) at B[k*ldb + n].  TRANSB=true: at B[n*ldb + k].
template <bool TRANSB>
__global__ __launch_bounds__(256)
void gemm_f32(const float* __restrict__ A, const float* __restrict__ Bm,
              const float* __restrict__ bias, float* __restrict__ Cm,
              int M, int N, int K, int lda, int ldb, int ldc) {
  __shared__ float As[16][68];
  __shared__ float Bs[16][68];
  const int bm = blockIdx.y * 64, bn = blockIdx.x * 64;
  const int tid = threadIdx.x;
  const int tm = (tid >> 4) << 2, tn = (tid & 15) << 2;
  float acc[4][4] = {};
  for (int k0 = 0; k0 < K; k0 += 16) {
#pragma unroll
    for (int e = tid; e < 1024; e += 256) {
      int m_l = e >> 4, k_l = e & 15;
      int m = bm + m_l, k = k0 + k_l;
      As[k_l][m_l] = (m < M && k < K) ? A[(size_t)m * lda + k] : 0.f;
    }
#pragma unroll
    for (int e = tid; e < 1024; e += 256) {
      int k_l, n_l; float v;
      if (TRANSB) {
        n_l = e >> 4; k_l = e & 15;
        int n = bn + n_l, k = k0 + k_l;
        v = (n < N && k < K) ? Bm[(size_t)n * ldb + k] : 0.f;
      } else {
        k_l = e >> 6; n_l = e & 63;
        int n = bn + n_l, k = k0 + k_l;
        v = (n < N && k < K) ? Bm[(size_t)k * ldb + n] : 0.f;
      }
      Bs[k_l][n_l] = v;
    }
    __syncthreads();
#pragma unroll
    for (int kk = 0; kk < 16; ++kk) {
      float av[4], bv[4];
#pragma unroll
      for (int i2 = 0; i2 < 4; ++i2) av[i2] = As[kk][tm + i2];
#pragma unroll
      for (int j2 = 0; j2 < 4; ++j2) bv[j2] = Bs[kk][tn + j2];
#pragma unroll
      for (int i2 = 0; i2 < 4; ++i2)
#pragma unroll
        for (int j2 = 0; j2 < 4; ++j2) acc[i2][j2] = fmaf(av[i2], bv[j2], acc[i2][j2]);
    }
    __syncthreads();
  }
#pragma unroll
  for (int i2 = 0; i2 < 4; ++i2)
#pragma unroll
    for (int j2 = 0; j2 < 4; ++j2) {
      int m = bm + tm + i2, n = bn + tn + j2;
      if (m < M && n < N)
        Cm[(size_t)m * ldc + n] = acc[i2][j2] + (bias ? bias[n] : 0.f);
    }
}

// ---------------- gather one directional sequence from xn (NHWC) ----------------
__global__ void seq_gather_k(const float* __restrict__ xn, float* __restrict__ seq,
                             int dir, int n) {
  for (int i = blockIdx.x * blockDim.x + threadIdx.x; i < n; i += gridDim.x * blockDim.x) {
    int c = i % 192;
    int l = (i / 192) & 4095;
    int b = i / (192 * 4096);
    int l2;
    if (dir == 0)      l2 = l;
    else if (dir == 1) l2 = 4095 - l;
    else if (dir == 2) l2 = ((l & 63) << 6) | (l >> 6);
    else { int s = 4095 - l; l2 = ((s & 63) << 6) | (s >> 6); }
    seq[i] = xn[((size_t)b * 4096 + l2) * 192 + c];
  }
}

// ---------------- causal depthwise conv K=4 + silu (region) ----------------
__global__ void conv_region_k(const float* __restrict__ xs, const float* __restrict__ w,
                              const float* __restrict__ cb, float* __restrict__ out, int n) {
  for (int i = blockIdx.x * blockDim.x + threadIdx.x; i < n; i += gridDim.x * blockDim.x) {
    int c = i % 192;
    int row = i / 192;
    int l = row & 4095;
    float acc = cb[c];
#pragma unroll
    for (int k = 0; k < 4; ++k) {
      int ls = l + k - 3;
      if (ls >= 0) acc = fmaf(xs[(size_t)(row + k - 3) * 192 + c], w[c * 4 + k], acc);
    }
    out[i] = siluf_(acc);
  }
}

// ---------------- causal depthwise conv K=2 + silu (local, per-window seqs of 64) ----------------
__global__ void conv_local_k(const float* __restrict__ xs, const float* __restrict__ w,
                             const float* __restrict__ cb, float* __restrict__ out, int n) {
  for (int i = blockIdx.x * blockDim.x + threadIdx.x; i < n; i += gridDim.x * blockDim.x) {
    int c = i % 192;
    int row = i / 192;
    int t = row & 63;
    float acc = fmaf(xs[(size_t)row * 192 + c], w[c * 2 + 1], cb[c]);
    if (t > 0) acc = fmaf(xs[(size_t)(row - 1) * 192 + c], w[c * 2 + 0], acc);
    out[i] = siluf_(acc);
  }
}

// ---------------- region selective scan: all 4 dirs x 4 batches, 1 channel/lane ----------------
__global__ __launch_bounds__(64)
void scan_region(const float* __restrict__ xc, const float* __restrict__ dbl,
                 float* __restrict__ zg,
                 const float* __restrict__ dt_w, const float* __restrict__ dt_b,
                 const float* __restrict__ Alog, const float* __restrict__ Dskip) {
  const int C = 192, L = 4096;
  int dir = blockIdx.x / 12;
  int b   = (blockIdx.x / 3) & 3;
  int grp = blockIdx.x % 3;
  int c = grp * 64 + threadIdx.x;
  float A[16], h[16], wdt[12];
#pragma unroll
  for (int nn = 0; nn < 16; ++nn) { A[nn] = -__expf(Alog[(size_t)(dir * C + c) * 16 + nn]); h[nn] = 0.f; }
#pragma unroll
  for (int r = 0; r < 12; ++r) wdt[r] = dt_w[(size_t)(dir * 12 + r) * C + c];
  float bdt = dt_b[dir * C + c];
  float Dv  = Dskip[dir * C + c];
  size_t rowbase = (size_t)(dir * 4 + b) * L;
  for (int t = 0; t < L; ++t) {
    size_t row = rowbase + t;
    const float* dd = dbl + row * 44;
    float dtr = bdt;
#pragma unroll
    for (int r = 0; r < 12; ++r) dtr = fmaf(dd[r], wdt[r], dtr);
    float dtv = softplusf_(dtr);
    float xv  = xc[row * C + c];
    float dx  = dtv * xv;
    float y = 0.f;
#pragma unroll
    for (int nn = 0; nn < 16; ++nn) {
      h[nn] = fmaf(__expf(dtv * A[nn]), h[nn], dx * dd[12 + nn]);
      y = fmaf(h[nn], dd[28 + nn], y);
    }
    y = fmaf(xv, Dv, y);
    float zv = zg[row * C + c];
    zg[row * C + c] = y * siluf_(zv);
  }
}

// ---------------- local selective scan: 256 windows, L=64, N=8 ----------------
__global__ __launch_bounds__(64)
void scan_local(const float* __restrict__ xc, const float* __restrict__ dbl,
                float* __restrict__ zg,
                const float* __restrict__ dt_w, const float* __restrict__ dt_b,
                const float* __restrict__ Alog, const float* __restrict__ Dskip) {
  const int C = 192, L = 64;
  int win = blockIdx.x / 3;
  int grp = blockIdx.x % 3;
  int c = grp * 64 + threadIdx.x;
  float A[8], h[8], wdt[12];
#pragma unroll
  for (int nn = 0; nn < 8; ++nn) { A[nn] = -__expf(Alog[(size_t)c * 8 + nn]); h[nn] = 0.f; }
#pragma unroll
  for (int r = 0; r < 12; ++r) wdt[r] = dt_w[(size_t)r * C + c];
  float bdt = dt_b[c];
  float Dv  = Dskip[c];
  size_t rowbase = (size_t)win * L;
  for (int t = 0; t < L; ++t) {
    size_t row = rowbase + t;
    const float* dd = dbl + row * 28;
    float dtr = bdt;
#pragma unroll
    for (int r = 0; r < 12; ++r) dtr = fmaf(dd[r], wdt[r], dtr);
    float dtv = softplusf_(dtr);
    float xv  = xc[row * C + c];
    float dx  = dtv * xv;
    float y = 0.f;
#pragma unroll
    for (int nn = 0; nn < 8; ++nn) {
      h[nn] = fmaf(__expf(dtv * A[nn]), h[nn], dx * dd[12 + nn]);
      y = fmaf(h[nn], dd[20 + nn], y);
    }
    y = fmaf(xv, Dv, y);
    float zv = zg[row * C + c];
    zg[row * C + c] = y * siluf_(zv);
  }
}

// ---------------- combine 4 directional outputs ----------------
__global__ void combine_k(const float* __restrict__ outr, const float* __restrict__ scale_mod,
                          float* __restrict__ reg, int n) {
  const size_t BLC = (size_t)4 * 4096 * 192;
  float sc = 0.25f * scale_mod[0];
  for (int i = blockIdx.x * blockDim.x + threadIdx.x; i < n; i += gridDim.x * blockDim.x) {
    int c = i % 192;
    int l = (i / 192) & 4095;
    int b = i / (192 * 4096);
    int hh = l >> 6, ww = l & 63;
    int lv = (ww << 6) | hh;
    size_t rb = (size_t)b * 4096;
    float v = outr[((rb + l) * 192) + c]
            + outr[BLC + ((rb + (4095 - l)) * 192) + c]
            + outr[2 * BLC + ((rb + lv) * 192) + c]
            + outr[3 * BLC + ((rb + (4095 - lv)) * 192) + c];
    reg[i] = v * sc;
  }
}

// ---------------- window gather: xn (NHWC) -> xw [win][t][c] ----------------
__global__ void win_gather_k(const float* __restrict__ xn, float* __restrict__ xw, int n) {
  for (int i = blockIdx.x * blockDim.x + threadIdx.x; i < n; i += gridDim.x * blockDim.x) {
    int c = i % 192;
    int t = (i / 192) & 63;
    int win = i / (192 * 64);
    int b = win >> 6, ih = (win >> 3) & 7, iw = win & 7;
    int p = t >> 3, q = t & 7;
    int hh = ih * 8 + p, ww = iw * 8 + q;
    xw[i] = xn[((size_t)(b * 4096) + hh * 64 + ww) * 192 + c];
  }
}

// ---------------- fused = region + local (un-window) ----------------
__global__ void fuse_k(float* __restrict__ fused, const float* __restrict__ outl, int n) {
  for (int i = blockIdx.x * blockDim.x + threadIdx.x; i < n; i += gridDim.x * blockDim.x) {
    int c = i % 192;
    int l = (i / 192) & 4095;
    int b = i / (192 * 4096);
    int hh = l >> 6, ww = l & 63;
    int win = ((b * 8 + (hh >> 3)) * 8) + (ww >> 3);
    int t = ((hh & 7) << 3) | (ww & 7);
    fused[i] += outl[((size_t)win * 64 + t) * 192 + c];
  }
}

// ---------------- depthwise 3x3 (SAME) + GLU ----------------
__global__ void dwglu_k(const float* __restrict__ h1, const float* __restrict__ dw_w,
                        const float* __restrict__ dw_b, float* __restrict__ glu, int n) {
  for (int i = blockIdx.x * blockDim.x + threadIdx.x; i < n; i += gridDim.x * blockDim.x) {
    int m = i % 384;
    int pix = i / 384;
    int p = pix & 4095, b = pix >> 12;
    int y = p >> 6, xx0 = p & 63;
    float a1 = dw_b[m], a2 = dw_b[m + 384];
#pragma unroll
    for (int dy = 0; dy < 3; ++dy) {
      int yy = y + dy - 1;
      if (yy < 0 || yy >= 64) continue;
#pragma unroll
      for (int dx = 0; dx < 3; ++dx) {
        int xx = xx0 + dx - 1;
        if (xx < 0 || xx >= 64) continue;
        const float* hp = h1 + ((size_t)(b * 4096) + yy * 64 + xx) * 768;
        a1 = fmaf(hp[m],       dw_w[(size_t)m * 9 + dy * 3 + dx],         a1);
        a2 = fmaf(hp[m + 384], dw_w[(size_t)(m + 384) * 9 + dy * 3 + dx], a2);
      }
    }
    glu[i] = a1 * sigmoidf_(a2);
  }
}

// ---------------- final: out = x + gamma*(fused + sgout), back to NCHW ----------------
__global__ void final_k(const float* __restrict__ x, const float* __restrict__ fused,
                        const float* __restrict__ sgout, const float* __restrict__ gamma,
                        float* __restrict__ out, int n) {
  float gm = gamma[0];
  for (int i = blockIdx.x * blockDim.x + threadIdx.x; i < n; i += gridDim.x * blockDim.x) {
    int p = i & 4095;
    int ch = (i >> 12) % 192;
    int b = i / (192 * 4096);
    size_t idx = ((size_t)(b * 4096) + p) * 192 + ch;
    out[i] = fmaf(gm, fused[idx] + sgout[idx], x[i]);
  }
}

extern "C" void kernel_launch(void* const* d_in, const int* in_sizes, int n_in,
                              void* d_out, int out_size, void* d_ws, size_t ws_size,
                              hipStream_t stream) {
  const float* x         = (const float*)d_in[0];
  const float* r_in_w    = (const float*)d_in[1];
  const float* r_conv_w  = (const float*)d_in[2];
  const float* r_conv_b  = (const float*)d_in[3];
  const float* r_xproj_w = (const float*)d_in[4];
  const float* r_dt_w    = (const float*)d_in[5];
  const float* r_dt_b    = (const float*)d_in[6];
  const float* r_Alog    = (const float*)d_in[7];
  const float* r_D       = (const float*)d_in[8];
  const float* r_out_w   = (const float*)d_in[9];
  const float* scale_mod = (const float*)d_in[10];
  const float* l_in_w    = (const float*)d_in[11];
  const float* l_conv_w  = (const float*)d_in[12];
  const float* l_conv_b  = (const float*)d_in[13];
  const float* l_xproj_w = (const float*)d_in[14];
  const float* l_dt_w    = (const float*)d_in[15];
  const float* l_dt_b    = (const float*)d_in[16];
  const float* l_Alog    = (const float*)d_in[17];
  const float* l_D       = (const float*)d_in[18];
  const float* l_out_w   = (const float*)d_in[19];
  const float* ln_g      = (const float*)d_in[20];
  const float* ln_b      = (const float*)d_in[21];
  const float* c1_w      = (const float*)d_in[22];
  const float* c1_b      = (const float*)d_in[23];
  const float* dw_w      = (const float*)d_in[24];
  const float* dw_b      = (const float*)d_in[25];
  const float* c2_w      = (const float*)d_in[26];
  const float* c2_b      = (const float*)d_in[27];
  const float* gamma     = (const float*)d_in[28];
  float* out = (float*)d_out;

  // Workspace arena (floats). Peak use = 12*BLC floats = 151 MB.
  float* W = (float*)d_ws;
  const size_t BLC = (size_t)4 * 4096 * 192;     // B*L*C = 3,145,728
  float* xn     = W;                 // [B*HW][C]
  float* seq    = W + BLC;           // transient: seq_d / xw
  float* fused  = W + 2 * BLC;       // transient xs_d; later region sum -> fused
  float* zall   = W + 3 * BLC;       // 4*BLC: z/g per dir; later zl/gl, then h1 (16384x768)
  float* xcall  = W + 7 * BLC;       // 4*BLC: xc per dir; later outr; later xsl/xcl/outl, glu/sgout
  float* dblall = W + 11 * BLC;      // 4*16384*44 (region) / 16384*28 (local)
  float* xs     = fused;             // alias for clarity in region loop

  auto gs = [](size_t n) { size_t g = (n + 255) / 256; return (int)(g > 8192 ? 8192 : g); };
  auto gemm = [&](const float* A, const float* Bm, const float* bias, float* Cm,
                  int M, int N, int K, int lda, int ldb, int ldc, bool transb) {
    dim3 g((N + 63) / 64, (M + 63) / 64), blk(256);
    if (transb) gemm_f32<true><<<g, blk, 0, stream>>>(A, Bm, bias, Cm, M, N, K, lda, ldb, ldc);
    else        gemm_f32<false><<<g, blk, 0, stream>>>(A, Bm, bias, Cm, M, N, K, lda, ldb, ldc);
  };
  const int nBLC = (int)BLC;

  // 1. LayerNorm  (NCHW -> NHWC)
  ln_kernel<<<dim3(256), dim3(256), 0, stream>>>(x, ln_g, ln_b, xn);

  // 2. Region branch: 4 directions
  for (int d = 0; d < 4; ++d) {
    seq_gather_k<<<gs(BLC), 256, 0, stream>>>(xn, seq, d, nBLC);
    gemm(seq, r_in_w + (size_t)d * 192 * 384,       nullptr, xs,             16384, 192, 192, 192, 384, 192, false);
    gemm(seq, r_in_w + (size_t)d * 192 * 384 + 192, nullptr, zall + d * BLC, 16384, 192, 192, 192, 384, 192, false);
    conv_region_k<<<gs(BLC), 256, 0, stream>>>(xs, r_conv_w + (size_t)d * 192 * 4,
                                               r_conv_b + (size_t)d * 192, xcall + d * BLC, nBLC);
    gemm(xcall + d * BLC, r_xproj_w + (size_t)d * 192 * 44, nullptr,
         dblall + (size_t)d * 16384 * 44, 16384, 44, 192, 192, 44, 44, false);
  }
  scan_region<<<48, 64, 0, stream>>>(xcall, dblall, zall, r_dt_w, r_dt_b, r_Alog, r_D);
  for (int d = 0; d < 4; ++d)
    gemm(zall + d * BLC, r_out_w + (size_t)d * 192 * 192, nullptr, xcall + d * BLC,
         16384, 192, 192, 192, 192, 192, false);
  combine_k<<<gs(BLC), 256, 0, stream>>>(xcall, scale_mod, fused, nBLC);

  // 3. Local windowed branch
  win_gather_k<<<gs(BLC), 256, 0, stream>>>(xn, seq, nBLC);
  gemm(seq, l_in_w,       nullptr, xcall,       16384, 192, 192, 192, 384, 192, false); // xsl
  gemm(seq, l_in_w + 192, nullptr, zall,        16384, 192, 192, 192, 384, 192, false); // zl
  conv_local_k<<<gs(BLC), 256, 0, stream>>>(xcall, l_conv_w, l_conv_b, xcall + BLC, nBLC); // xcl
  gemm(xcall + BLC, l_xproj_w, nullptr, dblall, 16384, 28, 192, 192, 28, 28, false);
  scan_local<<<768, 64, 0, stream>>>(xcall + BLC, dblall, zall, l_dt_w, l_dt_b, l_Alog, l_D);
  gemm(zall, l_out_w, nullptr, xcall + 2 * BLC, 16384, 192, 192, 192, 192, 192, false); // outl
  fuse_k<<<gs(BLC), 256, 0, stream>>>(fused, xcall + 2 * BLC, nBLC);

  // 4. SGFN + final residual
  gemm(fused, c1_w, c1_b, zall, 16384, 768, 192, 192, 192, 768, true);                  // h1 (NHWC)
  dwglu_k<<<gs((size_t)16384 * 384), 256, 0, stream>>>(zall, dw_w, dw_b, xcall, 16384 * 384);
  gemm(xcall, c2_w, c2_b, xcall + 2 * BLC, 16384, 192, 384, 384, 384, 192, true);       // sgout
  final_k<<<gs(BLC), 256, 0, stream>>>(x, fused, xcall + 2 * BLC, gamma, out, nBLC);
}

// Round 2
// 1375.631 us; speedup vs baseline: 3.5908x; 3.5908x over previous
//
#include <hip/hip_runtime.h>

#define DEV __device__ __forceinline__

DEV float sigmoidf_(float x) { return 1.f / (1.f + __expf(-x)); }
DEV float siluf_(float x)    { return x * sigmoidf_(x); }
DEV float softplusf_(float x){ return fmaxf(x, 0.f) + log1pf(__expf(-fabsf(x))); }

// ---------------- LayerNorm over C (NCHW in -> NHWC out) ----------------
__global__ __launch_bounds__(256)
void ln_kernel(const float* __restrict__ x, const float* __restrict__ g,
               const float* __restrict__ b, float* __restrict__ xn) {
  const int C = 192, HW = 4096;
  __shared__ float tile[64][193];
  __shared__ float red[2][4][64];
  __shared__ float mean_s[64], rstd_s[64];
  int bb = blockIdx.x >> 6;          // batch (64 tiles per batch)
  int p0 = (blockIdx.x & 63) << 6;   // pixel base
  int tid = threadIdx.x;
  int p = tid & 63, c4 = tid >> 6;
  for (int c = c4; c < C; c += 4)
    tile[p][c] = x[((size_t)(bb * C + c)) * HW + p0 + p];
  __syncthreads();
  float s = 0.f, s2 = 0.f;
  for (int c = c4 * 48; c < c4 * 48 + 48; ++c) { float v = tile[p][c]; s += v; s2 += v * v; }
  red[0][c4][p] = s; red[1][c4][p] = s2;
  __syncthreads();
  if (c4 == 0) {
    float ss = red[0][0][p] + red[0][1][p] + red[0][2][p] + red[0][3][p];
    float qq = red[1][0][p] + red[1][1][p] + red[1][2][p] + red[1][3][p];
    float m = ss * (1.f / 192.f);
    float var = qq * (1.f / 192.f) - m * m;
    mean_s[p] = m;
    rstd_s[p] = rsqrtf(var + 1e-5f);
  }
  __syncthreads();
  for (int e = tid; e < 64 * 192; e += 256) {
    int pp = e / 192, c = e % 192;
    xn[((size_t)bb * HW + p0 + pp) * C + c] =
        (tile[pp][c] - mean_s[pp]) * rstd_s[pp] * g[c] + b[c];
  }
}

// ---------------- Generic fp32 tiled GEMM: C[m,n] = sum_k A[m,k]*B(k,n) + bias[n] ----------------
template <bool TRANSB>
__global__ __launch_bounds__(256)
void gemm_f32(const float* __restrict__ A, const float* __restrict__ Bm,
              const float* __restrict__ bias, float* __restrict__ Cm,
              int M, int N, int K, int lda, int ldb, int ldc) {
  __shared__ float As[16][68];
  __shared__ float Bs[16][68];
  const int bm = blockIdx.y * 64, bn = blockIdx.x * 64;
  const int tid = threadIdx.x;
  const int tm = (tid >> 4) << 2, tn = (tid & 15) << 2;
  float acc[4][4] = {};
  for (int k0 = 0; k0 < K; k0 += 16) {
#pragma unroll
    for (int e = tid; e < 1024; e += 256) {
      int m_l = e >> 4, k_l = e & 15;
      int m = bm + m_l, k = k0 + k_l;
      As[k_l][m_l] = (m < M && k < K) ? A[(size_t)m * lda + k] : 0.f;
    }
#pragma unroll
    for (int e = tid; e < 1024; e += 256) {
      int k_l, n_l; float v;
      if (TRANSB) {
        n_l = e >> 4; k_l = e & 15;
        int n = bn + n_l, k = k0 + k_l;
        v = (n < N && k < K) ? Bm[(size_t)n * ldb + k] : 0.f;
      } else {
        k_l = e >> 6; n_l = e & 63;
        int n = bn + n_l, k = k0 + k_l;
        v = (n < N && k < K) ? Bm[(size_t)k * ldb + n] : 0.f;
      }
      Bs[k_l][n_l] = v;
    }
    __syncthreads();
#pragma unroll
    for (int kk = 0; kk < 16; ++kk) {
      float av[4], bv[4];
#pragma unroll
      for (int i2 = 0; i2 < 4; ++i2) av[i2] = As[kk][tm + i2];
#pragma unroll
      for (int j2 = 0; j2 < 4; ++j2) bv[j2] = Bs[kk][tn + j2];
#pragma unroll
      for (int i2 = 0; i2 < 4; ++i2)
#pragma unroll
        for (int j2 = 0; j2 < 4; ++j2) acc[i2][j2] = fmaf(av[i2], bv[j2], acc[i2][j2]);
    }
    __syncthreads();
  }
#pragma unroll
  for (int i2 = 0; i2 < 4; ++i2)
#pragma unroll
    for (int j2 = 0; j2 < 4; ++j2) {
      int m = bm + tm + i2, n = bn + tn + j2;
      if (m < M && n < N)
        Cm[(size_t)m * ldc + n] = acc[i2][j2] + (bias ? bias[n] : 0.f);
    }
}

// ---------------- gather one directional sequence from xn (NHWC) ----------------
__global__ void seq_gather_k(const float* __restrict__ xn, float* __restrict__ seq,
                             int dir, int n) {
  for (int i = blockIdx.x * blockDim.x + threadIdx.x; i < n; i += gridDim.x * blockDim.x) {
    int c = i % 192;
    int l = (i / 192) & 4095;
    int b = i / (192 * 4096);
    int l2;
    if (dir == 0)      l2 = l;
    else if (dir == 1) l2 = 4095 - l;
    else if (dir == 2) l2 = ((l & 63) << 6) | (l >> 6);
    else { int s = 4095 - l; l2 = ((s & 63) << 6) | (s >> 6); }
    seq[i] = xn[((size_t)b * 4096 + l2) * 192 + c];
  }
}

// ---------------- causal depthwise conv K=4 + silu (region) ----------------
__global__ void conv_region_k(const float* __restrict__ xs, const float* __restrict__ w,
                              const float* __restrict__ cb, float* __restrict__ out, int n) {
  for (int i = blockIdx.x * blockDim.x + threadIdx.x; i < n; i += gridDim.x * blockDim.x) {
    int c = i % 192;
    int row = i / 192;
    int l = row & 4095;
    float acc = cb[c];
#pragma unroll
    for (int k = 0; k < 4; ++k) {
      int ls = l + k - 3;
      if (ls >= 0) acc = fmaf(xs[(size_t)(row + k - 3) * 192 + c], w[c * 4 + k], acc);
    }
    out[i] = siluf_(acc);
  }
}

// ---------------- causal depthwise conv K=2 + silu (local) ----------------
__global__ void conv_local_k(const float* __restrict__ xs, const float* __restrict__ w,
                             const float* __restrict__ cb, float* __restrict__ out, int n) {
  for (int i = blockIdx.x * blockDim.x + threadIdx.x; i < n; i += gridDim.x * blockDim.x) {
    int c = i % 192;
    int row = i / 192;
    int t = row & 63;
    float acc = fmaf(xs[(size_t)row * 192 + c], w[c * 2 + 1], cb[c]);
    if (t > 0) acc = fmaf(xs[(size_t)(row - 1) * 192 + c], w[c * 2 + 0], acc);
    out[i] = siluf_(acc);
  }
}

// ======== region scan, chunked parallel version ========
// 16 seqs (dir*4+b), L=4096 split into 64 chunks of 64 steps. N=16, C=192.
// Pass A: per (seq,chunk,c): P[n] = prod a_t[n], H[n] = partial state (h_in=0).
// Pass B: per (seq,c,n): serial scan over 64 chunk carries; P <- h_in.
// Pass C: per (seq,chunk,c): replay chunk from h_in, emit g = y*silu(z).

__global__ __launch_bounds__(64)
void scan_chunkA(const float* __restrict__ xc, const float* __restrict__ dbl,
                 const float* __restrict__ dt_w, const float* __restrict__ dt_b,
                 const float* __restrict__ Alog,
                 float* __restrict__ Pc, float* __restrict__ Hc) {
  const int C = 192;
  int blk = blockIdx.x;            // seq*192 + chunk*3 + grp
  int grp = blk % 3;
  int chunk = (blk / 3) & 63;
  int seq = blk / 192;
  int dir = seq >> 2;
  int c = grp * 64 + threadIdx.x;
  float A[16], P[16], H[16], wdt[12];
#pragma unroll
  for (int nn = 0; nn < 16; ++nn) {
    A[nn] = -__expf(Alog[(size_t)(dir * C + c) * 16 + nn]);
    P[nn] = 1.f; H[nn] = 0.f;
  }
#pragma unroll
  for (int r = 0; r < 12; ++r) wdt[r] = dt_w[(size_t)(dir * 12 + r) * C + c];
  float bdt = dt_b[dir * C + c];
  size_t rowbase = (size_t)seq * 4096 + chunk * 64;
  for (int t = 0; t < 64; ++t) {
    size_t row = rowbase + t;
    const float* dd = dbl + row * 44;
    float dtr = bdt;
#pragma unroll
    for (int r = 0; r < 12; ++r) dtr = fmaf(dd[r], wdt[r], dtr);
    float dtv = softplusf_(dtr);
    float dx = dtv * xc[row * C + c];
#pragma unroll
    for (int nn = 0; nn < 16; ++nn) {
      float a = __expf(dtv * A[nn]);
      P[nn] *= a;
      H[nn] = fmaf(a, H[nn], dx * dd[12 + nn]);
    }
  }
  size_t ob = ((size_t)(seq * 64 + chunk) * C + c) * 16;
#pragma unroll
  for (int nn = 0; nn < 16; ++nn) { Pc[ob + nn] = P[nn]; Hc[ob + nn] = H[nn]; }
}

__global__ __launch_bounds__(256)
void scan_combine(float* __restrict__ Pc, const float* __restrict__ Hc) {
  int gid = blockIdx.x * 256 + threadIdx.x;   // 16*192*16 = 49152
  int nn = gid & 15;
  int c = (gid >> 4) % 192;
  int seq = gid / (192 * 16);
  float h = 0.f;
  for (int ch = 0; ch < 64; ++ch) {
    size_t idx = (((size_t)(seq * 64 + ch) * 192 + c) << 4) + nn;
    float nh = fmaf(Pc[idx], h, Hc[idx]);
    Pc[idx] = h;          // h_in for this chunk
    h = nh;
  }
}

__global__ __launch_bounds__(64)
void scan_chunkC(const float* __restrict__ xc, const float* __restrict__ dbl,
                 float* __restrict__ zg, const float* __restrict__ Pc,
                 const float* __restrict__ dt_w, const float* __restrict__ dt_b,
                 const float* __restrict__ Alog, const float* __restrict__ Dskip) {
  const int C = 192;
  int blk = blockIdx.x;
  int grp = blk % 3;
  int chunk = (blk / 3) & 63;
  int seq = blk / 192;
  int dir = seq >> 2;
  int c = grp * 64 + threadIdx.x;
  float A[16], h[16], wdt[12];
  size_t ob = ((size_t)(seq * 64 + chunk) * C + c) * 16;
#pragma unroll
  for (int nn = 0; nn < 16; ++nn) {
    A[nn] = -__expf(Alog[(size_t)(dir * C + c) * 16 + nn]);
    h[nn] = Pc[ob + nn];
  }
#pragma unroll
  for (int r = 0; r < 12; ++r) wdt[r] = dt_w[(size_t)(dir * 12 + r) * C + c];
  float bdt = dt_b[dir * C + c];
  float Dv  = Dskip[dir * C + c];
  size_t rowbase = (size_t)seq * 4096 + chunk * 64;
  for (int t = 0; t < 64; ++t) {
    size_t row = rowbase + t;
    const float* dd = dbl + row * 44;
    float dtr = bdt;
#pragma unroll
    for (int r = 0; r < 12; ++r) dtr = fmaf(dd[r], wdt[r], dtr);
    float dtv = softplusf_(dtr);
    float xv  = xc[row * C + c];
    float dx  = dtv * xv;
    float y = 0.f;
#pragma unroll
    for (int nn = 0; nn < 16; ++nn) {
      float a = __expf(dtv * A[nn]);
      h[nn] = fmaf(a, h[nn], dx * dd[12 + nn]);
      y = fmaf(h[nn], dd[28 + nn], y);
    }
    y = fmaf(xv, Dv, y);
    float zv = zg[row * C + c];
    zg[row * C + c] = y * siluf_(zv);
  }
}

// ---------------- local selective scan: 256 windows, L=64, N=8 ----------------
__global__ __launch_bounds__(64)
void scan_local(const float* __restrict__ xc, const float* __restrict__ dbl,
                float* __restrict__ zg,
                const float* __restrict__ dt_w, const float* __restrict__ dt_b,
                const float* __restrict__ Alog, const float* __restrict__ Dskip) {
  const int C = 192, L = 64;
  int win = blockIdx.x / 3;
  int grp = blockIdx.x % 3;
  int c = grp * 64 + threadIdx.x;
  float A[8], h[8], wdt[12];
#pragma unroll
  for (int nn = 0; nn < 8; ++nn) { A[nn] = -__expf(Alog[(size_t)c * 8 + nn]); h[nn] = 0.f; }
#pragma unroll
  for (int r = 0; r < 12; ++r) wdt[r] = dt_w[(size_t)r * C + c];
  float bdt = dt_b[c];
  float Dv  = Dskip[c];
  size_t rowbase = (size_t)win * L;
  for (int t = 0; t < L; ++t) {
    size_t row = rowbase + t;
    const float* dd = dbl + row * 28;
    float dtr = bdt;
#pragma unroll
    for (int r = 0; r < 12; ++r) dtr = fmaf(dd[r], wdt[r], dtr);
    float dtv = softplusf_(dtr);
    float xv  = xc[row * C + c];
    float dx  = dtv * xv;
    float y = 0.f;
#pragma unroll
    for (int nn = 0; nn < 8; ++nn) {
      h[nn] = fmaf(__expf(dtv * A[nn]), h[nn], dx * dd[12 + nn]);
      y = fmaf(h[nn], dd[20 + nn], y);
    }
    y = fmaf(xv, Dv, y);
    float zv = zg[row * C + c];
    zg[row * C + c] = y * siluf_(zv);
  }
}

// ---------------- combine 4 directional outputs ----------------
__global__ void combine_k(const float* __restrict__ outr, const float* __restrict__ scale_mod,
                          float* __restrict__ reg, int n) {
  const size_t BLC = (size_t)4 * 4096 * 192;
  float sc = 0.25f * scale_mod[0];
  for (int i = blockIdx.x * blockDim.x + threadIdx.x; i < n; i += gridDim.x * blockDim.x) {
    int c = i % 192;
    int l = (i / 192) & 4095;
    int b = i / (192 * 4096);
    int hh = l >> 6, ww = l & 63;
    int lv = (ww << 6) | hh;
    size_t rb = (size_t)b * 4096;
    float v = outr[((rb + l) * 192) + c]
            + outr[BLC + ((rb + (4095 - l)) * 192) + c]
            + outr[2 * BLC + ((rb + lv) * 192) + c]
            + outr[3 * BLC + ((rb + (4095 - lv)) * 192) + c];
    reg[i] = v * sc;
  }
}

// ---------------- window gather: xn (NHWC) -> xw [win][t][c] ----------------
__global__ void win_gather_k(const float* __restrict__ xn, float* __restrict__ xw, int n) {
  for (int i = blockIdx.x * blockDim.x + threadIdx.x; i < n; i += gridDim.x * blockDim.x) {
    int c = i % 192;
    int t = (i / 192) & 63;
    int win = i / (192 * 64);
    int b = win >> 6, ih = (win >> 3) & 7, iw = win & 7;
    int p = t >> 3, q = t & 7;
    int hh = ih * 8 + p, ww = iw * 8 + q;
    xw[i] = xn[((size_t)(b * 4096) + hh * 64 + ww) * 192 + c];
  }
}

// ---------------- fused = region + local (un-window) ----------------
__global__ void fuse_k(float* __restrict__ fused, const float* __restrict__ outl, int n) {
  for (int i = blockIdx.x * blockDim.x + threadIdx.x; i < n; i += gridDim.x * blockDim.x) {
    int c = i % 192;
    int l = (i / 192) & 4095;
    int b = i / (192 * 4096);
    int hh = l >> 6, ww = l & 63;
    int win = ((b * 8 + (hh >> 3)) * 8) + (ww >> 3);
    int t = ((hh & 7) << 3) | (ww & 7);
    fused[i] += outl[((size_t)win * 64 + t) * 192 + c];
  }
}

// ---------------- depthwise 3x3 (SAME) + GLU ----------------
__global__ void dwglu_k(const float* __restrict__ h1, const float* __restrict__ dw_w,
                        const float* __restrict__ dw_b, float* __restrict__ glu, int n) {
  for (int i = blockIdx.x * blockDim.x + threadIdx.x; i < n; i += gridDim.x * blockDim.x) {
    int m = i % 384;
    int pix = i / 384;
    int p = pix & 4095, b = pix >> 12;
    int y = p >> 6, xx0 = p & 63;
    float a1 = dw_b[m], a2 = dw_b[m + 384];
#pragma unroll
    for (int dy = 0; dy < 3; ++dy) {
      int yy = y + dy - 1;
      if (yy < 0 || yy >= 64) continue;
#pragma unroll
      for (int dx = 0; dx < 3; ++dx) {
        int xx = xx0 + dx - 1;
        if (xx < 0 || xx >= 64) continue;
        const float* hp = h1 + ((size_t)(b * 4096) + yy * 64 + xx) * 768;
        a1 = fmaf(hp[m],       dw_w[(size_t)m * 9 + dy * 3 + dx],         a1);
        a2 = fmaf(hp[m + 384], dw_w[(size_t)(m + 384) * 9 + dy * 3 + dx], a2);
      }
    }
    glu[i] = a1 * sigmoidf_(a2);
  }
}

// ---------------- final: out = x + gamma*(fused + sgout), back to NCHW ----------------
__global__ void final_k(const float* __restrict__ x, const float* __restrict__ fused,
                        const float* __restrict__ sgout, const float* __restrict__ gamma,
                        float* __restrict__ out, int n) {
  float gm = gamma[0];
  for (int i = blockIdx.x * blockDim.x + threadIdx.x; i < n; i += gridDim.x * blockDim.x) {
    int p = i & 4095;
    int ch = (i >> 12) % 192;
    int b = i / (192 * 4096);
    size_t idx = ((size_t)(b * 4096) + p) * 192 + ch;
    out[i] = fmaf(gm, fused[idx] + sgout[idx], x[i]);
  }
}

extern "C" void kernel_launch(void* const* d_in, const int* in_sizes, int n_in,
                              void* d_out, int out_size, void* d_ws, size_t ws_size,
                              hipStream_t stream) {
  const float* x         = (const float*)d_in[0];
  const float* r_in_w    = (const float*)d_in[1];
  const float* r_conv_w  = (const float*)d_in[2];
  const float* r_conv_b  = (const float*)d_in[3];
  const float* r_xproj_w = (const float*)d_in[4];
  const float* r_dt_w    = (const float*)d_in[5];
  const float* r_dt_b    = (const float*)d_in[6];
  const float* r_Alog    = (const float*)d_in[7];
  const float* r_D       = (const float*)d_in[8];
  const float* r_out_w   = (const float*)d_in[9];
  const float* scale_mod = (const float*)d_in[10];
  const float* l_in_w    = (const float*)d_in[11];
  const float* l_conv_w  = (const float*)d_in[12];
  const float* l_conv_b  = (const float*)d_in[13];
  const float* l_xproj_w = (const float*)d_in[14];
  const float* l_dt_w    = (const float*)d_in[15];
  const float* l_dt_b    = (const float*)d_in[16];
  const float* l_Alog    = (const float*)d_in[17];
  const float* l_D       = (const float*)d_in[18];
  const float* l_out_w   = (const float*)d_in[19];
  const float* ln_g      = (const float*)d_in[20];
  const float* ln_b      = (const float*)d_in[21];
  const float* c1_w      = (const float*)d_in[22];
  const float* c1_b      = (const float*)d_in[23];
  const float* dw_w      = (const float*)d_in[24];
  const float* dw_b      = (const float*)d_in[25];
  const float* c2_w      = (const float*)d_in[26];
  const float* c2_b      = (const float*)d_in[27];
  const float* gamma     = (const float*)d_in[28];
  float* out = (float*)d_out;

  // Workspace arena (floats). Peak use = 12*BLC floats = 151 MB.
  float* W = (float*)d_ws;
  const size_t BLC = (size_t)4 * 4096 * 192;     // B*L*C = 3,145,728
  float* xn     = W;                 // [B*HW][C]
  float* seq    = W + BLC;           // transient: seq_d / xw ; P-carries during region scan
  float* fused  = W + 2 * BLC;       // transient xs_d / H-carries ; later region sum -> fused
  float* zall   = W + 3 * BLC;       // 4*BLC: z/g per dir; later zl/gl, then h1 (16384x768)
  float* xcall  = W + 7 * BLC;       // 4*BLC: xc per dir; later outr; later local bufs
  float* dblall = W + 11 * BLC;      // 4*16384*44 (region) / 16384*28 (local)
  float* xs     = fused;             // conv input alias (dead before scan)
  float* Pc     = seq;               // [16][64][192][16] = BLC floats (chunk decay / h_in)
  float* Hc     = fused;             // [16][64][192][16] = BLC floats (chunk partial state)

  auto gs = [](size_t n) { size_t g = (n + 255) / 256; return (int)(g > 8192 ? 8192 : g); };
  auto gemm = [&](const float* A, const float* Bm, const float* bias, float* Cm,
                  int M, int N, int K, int lda, int ldb, int ldc, bool transb) {
    dim3 g((N + 63) / 64, (M + 63) / 64), blk(256);
    if (transb) gemm_f32<true><<<g, blk, 0, stream>>>(A, Bm, bias, Cm, M, N, K, lda, ldb, ldc);
    else        gemm_f32<false><<<g, blk, 0, stream>>>(A, Bm, bias, Cm, M, N, K, lda, ldb, ldc);
  };
  const int nBLC = (int)BLC;

  // 1. LayerNorm  (NCHW -> NHWC)
  ln_kernel<<<dim3(256), dim3(256), 0, stream>>>(x, ln_g, ln_b, xn);

  // 2. Region branch: 4 directions
  for (int d = 0; d < 4; ++d) {
    seq_gather_k<<<gs(BLC), 256, 0, stream>>>(xn, seq, d, nBLC);
    gemm(seq, r_in_w + (size_t)d * 192 * 384,       nullptr, xs,             16384, 192, 192, 192, 384, 192, false);
    gemm(seq, r_in_w + (size_t)d * 192 * 384 + 192, nullptr, zall + d * BLC, 16384, 192, 192, 192, 384, 192, false);
    conv_region_k<<<gs(BLC), 256, 0, stream>>>(xs, r_conv_w + (size_t)d * 192 * 4,
                                               r_conv_b + (size_t)d * 192, xcall + d * BLC, nBLC);
    gemm(xcall + d * BLC, r_xproj_w + (size_t)d * 192 * 44, nullptr,
         dblall + (size_t)d * 16384 * 44, 16384, 44, 192, 192, 44, 44, false);
  }
  // chunked parallel scan (replaces serial scan_region)
  scan_chunkA<<<3072, 64, 0, stream>>>(xcall, dblall, r_dt_w, r_dt_b, r_Alog, Pc, Hc);
  scan_combine<<<192, 256, 0, stream>>>(Pc, Hc);
  scan_chunkC<<<3072, 64, 0, stream>>>(xcall, dblall, zall, Pc, r_dt_w, r_dt_b, r_Alog, r_D);
  for (int d = 0; d < 4; ++d)
    gemm(zall + d * BLC, r_out_w + (size_t)d * 192 * 192, nullptr, xcall + d * BLC,
         16384, 192, 192, 192, 192, 192, false);
  combine_k<<<gs(BLC), 256, 0, stream>>>(xcall, scale_mod, fused, nBLC);

  // 3. Local windowed branch
  win_gather_k<<<gs(BLC), 256, 0, stream>>>(xn, seq, nBLC);
  gemm(seq, l_in_w,       nullptr, xcall,       16384, 192, 192, 192, 384, 192, false); // xsl
  gemm(seq, l_in_w + 192, nullptr, zall,        16384, 192, 192, 192, 384, 192, false); // zl
  conv_local_k<<<gs(BLC), 256, 0, stream>>>(xcall, l_conv_w, l_conv_b, xcall + BLC, nBLC); // xcl
  gemm(xcall + BLC, l_xproj_w, nullptr, dblall, 16384, 28, 192, 192, 28, 28, false);
  scan_local<<<768, 64, 0, stream>>>(xcall + BLC, dblall, zall, l_dt_w, l_dt_b, l_Alog, l_D);
  gemm(zall, l_out_w, nullptr, xcall + 2 * BLC, 16384, 192, 192, 192, 192, 192, false); // outl
  fuse_k<<<gs(BLC), 256, 0, stream>>>(fused, xcall + 2 * BLC, nBLC);

  // 4. SGFN + final residual
  gemm(fused, c1_w, c1_b, zall, 16384, 768, 192, 192, 192, 768, true);                  // h1 (NHWC)
  dwglu_k<<<gs((size_t)16384 * 384), 256, 0, stream>>>(zall, dw_w, dw_b, xcall, 16384 * 384);
  gemm(xcall, c2_w, c2_b, xcall + 2 * BLC, 16384, 192, 384, 384, 384, 192, true);       // sgout
  final_k<<<gs(BLC), 256, 0, stream>>>(x, fused, xcall + 2 * BLC, gamma, out, nBLC);
}

// Round 3
// 770.749 us; speedup vs baseline: 6.4088x; 1.7848x over previous
//
#include <hip/hip_runtime.h>

typedef unsigned short ushortT;
typedef unsigned int uintT;
typedef __bf16 bf16x8 __attribute__((ext_vector_type(8)));
typedef short short8v __attribute__((ext_vector_type(8)));
typedef float f32x4 __attribute__((ext_vector_type(4)));
typedef float float4v __attribute__((ext_vector_type(4)));

#define DEV __device__ __forceinline__

DEV float sigmoidf_(float x) { return 1.f / (1.f + __expf(-x)); }
DEV float siluf_(float x)    { return x * sigmoidf_(x); }
DEV float softplusf_(float x){ return fmaxf(x, 0.f) + log1pf(__expf(-fabsf(x))); }

DEV ushortT f2bf(float f) {
  union { float f; uintT u; } x; x.f = f;
  uintT u = x.u + 0x7fffu + ((x.u >> 16) & 1u);
  return (ushortT)(u >> 16);
}
DEV float bf2f(ushortT h) {
  union { uintT u; float f; } x; x.u = ((uintT)h) << 16;
  return x.f;
}

// ---------------- LayerNorm over C (NCHW in -> NHWC out, fp32) ----------------
__global__ __launch_bounds__(256)
void ln_kernel(const float* __restrict__ x, const float* __restrict__ g,
               const float* __restrict__ b, float* __restrict__ xn) {
  const int C = 192, HW = 4096;
  __shared__ float tile[64][193];
  __shared__ float red[2][4][64];
  __shared__ float mean_s[64], rstd_s[64];
  int bb = blockIdx.x >> 6;
  int p0 = (blockIdx.x & 63) << 6;
  int tid = threadIdx.x;
  int p = tid & 63, c4 = tid >> 6;
  for (int c = c4; c < C; c += 4)
    tile[p][c] = x[((size_t)(bb * C + c)) * HW + p0 + p];
  __syncthreads();
  float s = 0.f, s2 = 0.f;
  for (int c = c4 * 48; c < c4 * 48 + 48; ++c) { float v = tile[p][c]; s += v; s2 += v * v; }
  red[0][c4][p] = s; red[1][c4][p] = s2;
  __syncthreads();
  if (c4 == 0) {
    float ss = red[0][0][p] + red[0][1][p] + red[0][2][p] + red[0][3][p];
    float qq = red[1][0][p] + red[1][1][p] + red[1][2][p] + red[1][3][p];
    float m = ss * (1.f / 192.f);
    float var = qq * (1.f / 192.f) - m * m;
    mean_s[p] = m;
    rstd_s[p] = rsqrtf(var + 1e-5f);
  }
  __syncthreads();
  for (int e = tid; e < 64 * 192; e += 256) {
    int pp = e / 192, c = e % 192;
    xn[((size_t)bb * HW + p0 + pp) * C + c] =
        (tile[pp][c] - mean_s[pp]) * rstd_s[pp] * g[c] + b[c];
  }
}

// ---------------- weight prep: cast/transpose all GEMM B operands to bf16 [N][K] ----------------
__global__ __launch_bounds__(256)
void prep_w(const float* __restrict__ r_in_w, const float* __restrict__ r_xproj_w,
            const float* __restrict__ r_out_w, const float* __restrict__ l_in_w,
            const float* __restrict__ l_xproj_w, const float* __restrict__ l_out_w,
            const float* __restrict__ c1_w, const float* __restrict__ c2_w,
            ushortT* __restrict__ wbf) {
  int i = blockIdx.x * 256 + threadIdx.x;
  if (i >= 813312) return;
  float v;
  if (i < 294912) {                 // r_in_w [192][384] -> [384][192] x4
    int d = i / 73728, j = i % 73728, n = j / 192, k = j % 192;
    v = r_in_w[(size_t)d * 73728 + k * 384 + n];
  } else if (i < 328704) {          // r_xproj [192][44] -> [44][192] x4
    int j = i - 294912; int d = j / 8448, jj = j % 8448, n = jj / 192, k = jj % 192;
    v = r_xproj_w[(size_t)d * 8448 + k * 44 + n];
  } else if (i < 476160) {          // r_out [192][192] -> [192][192]^T x4
    int j = i - 328704; int d = j / 36864, jj = j % 36864, n = jj / 192, k = jj % 192;
    v = r_out_w[(size_t)d * 36864 + k * 192 + n];
  } else if (i < 549888) {          // l_in_w [192][384] -> [384][192]
    int j = i - 476160; int n = j / 192, k = j % 192;
    v = l_in_w[k * 384 + n];
  } else if (i < 555264) {          // l_xproj [192][28] -> [28][192]
    int j = i - 549888; int n = j / 192, k = j % 192;
    v = l_xproj_w[k * 28 + n];
  } else if (i < 592128) {          // l_out [192][192]^T
    int j = i - 555264; int n = j / 192, k = j % 192;
    v = l_out_w[k * 192 + n];
  } else if (i < 739584) {          // c1_w [768][192] already [N][K]
    v = c1_w[i - 592128];
  } else {                          // c2_w [192][384] already [N][K]
    v = c2_w[i - 739584];
  }
  wbf[i] = f2bf(v);
}

// ---------------- A-row permutations (gather fused into GEMM) ----------------
template <int PERM> DEV int permrow(int m) {
  if (PERM == 0) return m;
  int b = m >> 12, l = m & 4095;
  if (PERM == 1) return (b << 12) | (4095 - l);
  if (PERM == 2) return (b << 12) | (((l & 63) << 6) | (l >> 6));
  if (PERM == 3) { int s = 4095 - l; return (b << 12) | (((s & 63) << 6) | (s >> 6)); }
  // PERM==4: 8x8 window order
  int ih = (m >> 9) & 7, iw = (m >> 6) & 7, p = (m >> 3) & 7, q = m & 7;
  return (b << 12) | ((((ih << 3) | p) << 6) | ((iw << 3) | q));
}

// ---------------- MFMA bf16 GEMM: C[M,N] = A[M,K] * B^T(bf16 [N][K]) + bias ----------------
// BK = 192 per LDS stage; lda == K, ldc == N. M % BM == 0.
template <int PERM, int ABF16, int CBF16, int BM>
__global__ __launch_bounds__(256)
void gemm_mfma(const void* __restrict__ Ap, const ushortT* __restrict__ Bw,
               const float* __restrict__ bias, void* __restrict__ Cp,
               int M, int N, int K, int nbn) {
  __shared__ __align__(16) ushortT As[BM * 192];
  __shared__ __align__(16) ushortT Bs[64 * 192];
  int nwg = gridDim.x;
  int bid = blockIdx.x;
  int q = nwg >> 3, r = nwg & 7, xq = bid & 7, o = bid >> 3;
  int wg = (xq < r ? xq * (q + 1) : r * (q + 1) + (xq - r) * q) + o;
  int bn = (wg % nbn) * 64;
  int bm = (wg / nbn) * BM;
  int tid = threadIdx.x;
  int lane = tid & 63, w = tid >> 6;
  constexpr int MF = BM / 32;
  int wm = (w >> 1) * (MF * 16), wn = (w & 1) * 32;
  f32x4 acc[MF][2] = {};

  for (int k0 = 0; k0 < K; k0 += 192) {
    // stage A (BM x 192), 16B slots, XOR swizzle on low-3 slot bits
    for (int ci = tid; ci < BM * 24; ci += 256) {
      int row = ci / 24, s = ci - row * 24;
      int srow = permrow<PERM>(bm + row);
      int sw = (s & ~7) | ((s ^ row) & 7);
      short8v v;
      if (ABF16) {
        v = *(const short8v*)((const ushortT*)Ap + (size_t)srow * K + k0 + s * 8);
      } else {
        const float* af = (const float*)Ap + (size_t)srow * K + k0 + s * 8;
        float4v f0 = *(const float4v*)af;
        float4v f1 = *(const float4v*)(af + 4);
#pragma unroll
        for (int j = 0; j < 4; ++j) v[j] = (short)f2bf(f0[j]);
#pragma unroll
        for (int j = 0; j < 4; ++j) v[4 + j] = (short)f2bf(f1[j]);
      }
      *(short8v*)&As[row * 192 + sw * 8] = v;
    }
    // stage B (64 x 192) from [N][K] bf16 weights
    for (int ci = tid; ci < 64 * 24; ci += 256) {
      int row = ci / 24, s = ci - row * 24;
      int n = bn + row;
      int sw = (s & ~7) | ((s ^ row) & 7);
      short8v v = {};
      if (n < N) v = *(const short8v*)(Bw + (size_t)n * K + k0 + s * 8);
      *(short8v*)&Bs[row * 192 + sw * 8] = v;
    }
    __syncthreads();
#pragma unroll
    for (int kk = 0; kk < 6; ++kk) {
      int sbase = kk * 4 + (lane >> 4);
      bf16x8 a[MF], bfr[2];
#pragma unroll
      for (int mf = 0; mf < MF; ++mf) {
        int rw = wm + mf * 16 + (lane & 15);
        int sw = (sbase & ~7) | ((sbase ^ rw) & 7);
        a[mf] = __builtin_bit_cast(bf16x8, *(const short8v*)&As[rw * 192 + sw * 8]);
      }
#pragma unroll
      for (int nf = 0; nf < 2; ++nf) {
        int rw = wn + nf * 16 + (lane & 15);
        int sw = (sbase & ~7) | ((sbase ^ rw) & 7);
        bfr[nf] = __builtin_bit_cast(bf16x8, *(const short8v*)&Bs[rw * 192 + sw * 8]);
      }
#pragma unroll
      for (int mf = 0; mf < MF; ++mf)
#pragma unroll
        for (int nf = 0; nf < 2; ++nf)
          acc[mf][nf] = __builtin_amdgcn_mfma_f32_16x16x32_bf16(a[mf], bfr[nf], acc[mf][nf], 0, 0, 0);
    }
    __syncthreads();
  }
  // epilogue: row=(lane>>4)*4+j, col=lane&15
#pragma unroll
  for (int mf = 0; mf < MF; ++mf)
#pragma unroll
    for (int nf = 0; nf < 2; ++nf)
#pragma unroll
      for (int j = 0; j < 4; ++j) {
        int rowg = bm + wm + mf * 16 + ((lane >> 4) << 2) + j;
        int colg = bn + wn + nf * 16 + (lane & 15);
        if (colg < N) {
          float v2 = acc[mf][nf][j] + (bias ? bias[colg] : 0.f);
          if (CBF16) ((ushortT*)Cp)[(size_t)rowg * N + colg] = f2bf(v2);
          else       ((float*)Cp)[(size_t)rowg * N + colg]  = v2;
        }
      }
}

// ---------------- causal depthwise conv K=4 + silu (region) ----------------
__global__ void conv_region_k(const float* __restrict__ xs, const float* __restrict__ w,
                              const float* __restrict__ cb, float* __restrict__ out, int n) {
  for (int i = blockIdx.x * blockDim.x + threadIdx.x; i < n; i += gridDim.x * blockDim.x) {
    int c = i % 192;
    int row = i / 192;
    int l = row & 4095;
    float acc = cb[c];
#pragma unroll
    for (int k = 0; k < 4; ++k) {
      int ls = l + k - 3;
      if (ls >= 0) acc = fmaf(xs[(size_t)(row + k - 3) * 192 + c], w[c * 4 + k], acc);
    }
    out[i] = siluf_(acc);
  }
}

// ---------------- causal depthwise conv K=2 + silu (local) ----------------
__global__ void conv_local_k(const float* __restrict__ xs, const float* __restrict__ w,
                             const float* __restrict__ cb, float* __restrict__ out, int n) {
  for (int i = blockIdx.x * blockDim.x + threadIdx.x; i < n; i += gridDim.x * blockDim.x) {
    int c = i % 192;
    int row = i / 192;
    int t = row & 63;
    float acc = fmaf(xs[(size_t)row * 192 + c], w[c * 2 + 1], cb[c]);
    if (t > 0) acc = fmaf(xs[(size_t)(row - 1) * 192 + c], w[c * 2 + 0], acc);
    out[i] = siluf_(acc);
  }
}

// ======== region scan, chunked parallel (64 chunks of 64) ========
__global__ __launch_bounds__(64)
void scan_chunkA(const float* __restrict__ xc, const float* __restrict__ dbl,
                 const float* __restrict__ dt_w, const float* __restrict__ dt_b,
                 const float* __restrict__ Alog,
                 float* __restrict__ Pc, float* __restrict__ Hc) {
  const int C = 192;
  int blk = blockIdx.x;
  int grp = blk % 3;
  int chunk = (blk / 3) & 63;
  int seq = blk / 192;
  int dir = seq >> 2;
  int c = grp * 64 + threadIdx.x;
  float A[16], P[16], H[16], wdt[12];
#pragma unroll
  for (int nn = 0; nn < 16; ++nn) {
    A[nn] = -__expf(Alog[(size_t)(dir * C + c) * 16 + nn]);
    P[nn] = 1.f; H[nn] = 0.f;
  }
#pragma unroll
  for (int r = 0; r < 12; ++r) wdt[r] = dt_w[(size_t)(dir * 12 + r) * C + c];
  float bdt = dt_b[dir * C + c];
  size_t rowbase = (size_t)seq * 4096 + chunk * 64;
  for (int t = 0; t < 64; ++t) {
    size_t row = rowbase + t;
    const float* dd = dbl + row * 44;
    float dtr = bdt;
#pragma unroll
    for (int r = 0; r < 12; ++r) dtr = fmaf(dd[r], wdt[r], dtr);
    float dtv = softplusf_(dtr);
    float dx = dtv * xc[row * C + c];
#pragma unroll
    for (int nn = 0; nn < 16; ++nn) {
      float a = __expf(dtv * A[nn]);
      P[nn] *= a;
      H[nn] = fmaf(a, H[nn], dx * dd[12 + nn]);
    }
  }
  size_t ob = ((size_t)(seq * 64 + chunk) * C + c) * 16;
#pragma unroll
  for (int nn = 0; nn < 16; ++nn) { Pc[ob + nn] = P[nn]; Hc[ob + nn] = H[nn]; }
}

__global__ __launch_bounds__(256)
void scan_combine(float* __restrict__ Pc, const float* __restrict__ Hc) {
  int gid = blockIdx.x * 256 + threadIdx.x;   // 16*192*16 = 49152
  int nn = gid & 15;
  int c = (gid >> 4) % 192;
  int seq = gid / (192 * 16);
  float h = 0.f;
  for (int ch = 0; ch < 64; ++ch) {
    size_t idx = (((size_t)(seq * 64 + ch) * 192 + c) << 4) + nn;
    float nh = fmaf(Pc[idx], h, Hc[idx]);
    Pc[idx] = h;
    h = nh;
  }
}

__global__ __launch_bounds__(64)
void scan_chunkC(const float* __restrict__ xc, const float* __restrict__ dbl,
                 ushortT* __restrict__ zg, const float* __restrict__ Pc,
                 const float* __restrict__ dt_w, const float* __restrict__ dt_b,
                 const float* __restrict__ Alog, const float* __restrict__ Dskip) {
  const int C = 192;
  int blk = blockIdx.x;
  int grp = blk % 3;
  int chunk = (blk / 3) & 63;
  int seq = blk / 192;
  int dir = seq >> 2;
  int c = grp * 64 + threadIdx.x;
  float A[16], h[16], wdt[12];
  size_t ob = ((size_t)(seq * 64 + chunk) * C + c) * 16;
#pragma unroll
  for (int nn = 0; nn < 16; ++nn) {
    A[nn] = -__expf(Alog[(size_t)(dir * C + c) * 16 + nn]);
    h[nn] = Pc[ob + nn];
  }
#pragma unroll
  for (int r = 0; r < 12; ++r) wdt[r] = dt_w[(size_t)(dir * 12 + r) * C + c];
  float bdt = dt_b[dir * C + c];
  float Dv  = Dskip[dir * C + c];
  size_t rowbase = (size_t)seq * 4096 + chunk * 64;
  for (int t = 0; t < 64; ++t) {
    size_t row = rowbase + t;
    const float* dd = dbl + row * 44;
    float dtr = bdt;
#pragma unroll
    for (int r = 0; r < 12; ++r) dtr = fmaf(dd[r], wdt[r], dtr);
    float dtv = softplusf_(dtr);
    float xv  = xc[row * C + c];
    float dx  = dtv * xv;
    float y = 0.f;
#pragma unroll
    for (int nn = 0; nn < 16; ++nn) {
      float a = __expf(dtv * A[nn]);
      h[nn] = fmaf(a, h[nn], dx * dd[12 + nn]);
      y = fmaf(h[nn], dd[28 + nn], y);
    }
    y = fmaf(xv, Dv, y);
    float zv = bf2f(zg[row * C + c]);
    zg[row * C + c] = f2bf(y * siluf_(zv));
  }
}

// ---------------- local selective scan: 256 windows, L=64, N=8 ----------------
__global__ __launch_bounds__(64)
void scan_local(const float* __restrict__ xc, const float* __restrict__ dbl,
                ushortT* __restrict__ zg,
                const float* __restrict__ dt_w, const float* __restrict__ dt_b,
                const float* __restrict__ Alog, const float* __restrict__ Dskip) {
  const int C = 192, L = 64;
  int win = blockIdx.x / 3;
  int grp = blockIdx.x % 3;
  int c = grp * 64 + threadIdx.x;
  float A[8], h[8], wdt[12];
#pragma unroll
  for (int nn = 0; nn < 8; ++nn) { A[nn] = -__expf(Alog[(size_t)c * 8 + nn]); h[nn] = 0.f; }
#pragma unroll
  for (int r = 0; r < 12; ++r) wdt[r] = dt_w[(size_t)r * C + c];
  float bdt = dt_b[c];
  float Dv  = Dskip[c];
  size_t rowbase = (size_t)win * L;
  for (int t = 0; t < L; ++t) {
    size_t row = rowbase + t;
    const float* dd = dbl + row * 28;
    float dtr = bdt;
#pragma unroll
    for (int r = 0; r < 12; ++r) dtr = fmaf(dd[r], wdt[r], dtr);
    float dtv = softplusf_(dtr);
    float xv  = xc[row * C + c];
    float dx  = dtv * xv;
    float y = 0.f;
#pragma unroll
    for (int nn = 0; nn < 8; ++nn) {
      h[nn] = fmaf(__expf(dtv * A[nn]), h[nn], dx * dd[12 + nn]);
      y = fmaf(h[nn], dd[20 + nn], y);
    }
    y = fmaf(xv, Dv, y);
    float zv = bf2f(zg[row * C + c]);
    zg[row * C + c] = f2bf(y * siluf_(zv));
  }
}

// ---------------- combine 4 directional outputs ----------------
__global__ void combine_k(const float* __restrict__ outr, const float* __restrict__ scale_mod,
                          float* __restrict__ reg, int n) {
  const size_t BLC = (size_t)4 * 4096 * 192;
  float sc = 0.25f * scale_mod[0];
  for (int i = blockIdx.x * blockDim.x + threadIdx.x; i < n; i += gridDim.x * blockDim.x) {
    int c = i % 192;
    int l = (i / 192) & 4095;
    int b = i / (192 * 4096);
    int hh = l >> 6, ww = l & 63;
    int lv = (ww << 6) | hh;
    size_t rb = (size_t)b * 4096;
    float v = outr[((rb + l) * 192) + c]
            + outr[BLC + ((rb + (4095 - l)) * 192) + c]
            + outr[2 * BLC + ((rb + lv) * 192) + c]
            + outr[3 * BLC + ((rb + (4095 - lv)) * 192) + c];
    reg[i] = v * sc;
  }
}

// ---------------- fused = region + local (un-window) ----------------
__global__ void fuse_k(float* __restrict__ fused, const float* __restrict__ outl, int n) {
  for (int i = blockIdx.x * blockDim.x + threadIdx.x; i < n; i += gridDim.x * blockDim.x) {
    int c = i % 192;
    int l = (i / 192) & 4095;
    int b = i / (192 * 4096);
    int hh = l >> 6, ww = l & 63;
    int win = ((b * 8 + (hh >> 3)) * 8) + (ww >> 3);
    int t = ((hh & 7) << 3) | (ww & 7);
    fused[i] += outl[((size_t)win * 64 + t) * 192 + c];
  }
}

// ---------------- depthwise 3x3 (SAME) + GLU ----------------
__global__ void dwglu_k(const float* __restrict__ h1, const float* __restrict__ dw_w,
                        const float* __restrict__ dw_b, float* __restrict__ glu, int n) {
  for (int i = blockIdx.x * blockDim.x + threadIdx.x; i < n; i += gridDim.x * blockDim.x) {
    int m = i % 384;
    int pix = i / 384;
    int p = pix & 4095, b = pix >> 12;
    int y = p >> 6, xx0 = p & 63;
    float a1 = dw_b[m], a2 = dw_b[m + 384];
#pragma unroll
    for (int dy = 0; dy < 3; ++dy) {
      int yy = y + dy - 1;
      if (yy < 0 || yy >= 64) continue;
#pragma unroll
      for (int dx = 0; dx < 3; ++dx) {
        int xx = xx0 + dx - 1;
        if (xx < 0 || xx >= 64) continue;
        const float* hp = h1 + ((size_t)(b * 4096) + yy * 64 + xx) * 768;
        a1 = fmaf(hp[m],       dw_w[(size_t)m * 9 + dy * 3 + dx],         a1);
        a2 = fmaf(hp[m + 384], dw_w[(size_t)(m + 384) * 9 + dy * 3 + dx], a2);
      }
    }
    glu[i] = a1 * sigmoidf_(a2);
  }
}

// ---------------- final: out = x + gamma*(fused + sgout), back to NCHW ----------------
__global__ void final_k(const float* __restrict__ x, const float* __restrict__ fused,
                        const float* __restrict__ sgout, const float* __restrict__ gamma,
                        float* __restrict__ out, int n) {
  float gm = gamma[0];
  for (int i = blockIdx.x * blockDim.x + threadIdx.x; i < n; i += gridDim.x * blockDim.x) {
    int p = i & 4095;
    int ch = (i >> 12) % 192;
    int b = i / (192 * 4096);
    size_t idx = ((size_t)(b * 4096) + p) * 192 + ch;
    out[i] = fmaf(gm, fused[idx] + sgout[idx], x[i]);
  }
}

extern "C" void kernel_launch(void* const* d_in, const int* in_sizes, int n_in,
                              void* d_out, int out_size, void* d_ws, size_t ws_size,
                              hipStream_t stream) {
  const float* x         = (const float*)d_in[0];
  const float* r_in_w    = (const float*)d_in[1];
  const float* r_conv_w  = (const float*)d_in[2];
  const float* r_conv_b  = (const float*)d_in[3];
  const float* r_xproj_w = (const float*)d_in[4];
  const float* r_dt_w    = (const float*)d_in[5];
  const float* r_dt_b    = (const float*)d_in[6];
  const float* r_Alog    = (const float*)d_in[7];
  const float* r_D       = (const float*)d_in[8];
  const float* r_out_w   = (const float*)d_in[9];
  const float* scale_mod = (const float*)d_in[10];
  const float* l_in_w    = (const float*)d_in[11];
  const float* l_conv_w  = (const float*)d_in[12];
  const float* l_conv_b  = (const float*)d_in[13];
  const float* l_xproj_w = (const float*)d_in[14];
  const float* l_dt_w    = (const float*)d_in[15];
  const float* l_dt_b    = (const float*)d_in[16];
  const float* l_Alog    = (const float*)d_in[17];
  const float* l_D       = (const float*)d_in[18];
  const float* l_out_w   = (const float*)d_in[19];
  const float* ln_g      = (const float*)d_in[20];
  const float* ln_b      = (const float*)d_in[21];
  const float* c1_w      = (const float*)d_in[22];
  const float* c1_b      = (const float*)d_in[23];
  const float* dw_w      = (const float*)d_in[24];
  const float* dw_b      = (const float*)d_in[25];
  const float* c2_w      = (const float*)d_in[26];
  const float* c2_b      = (const float*)d_in[27];
  const float* gamma     = (const float*)d_in[28];
  float* out = (float*)d_out;

  // Workspace arena (floats). Total = 9*BLC + 3,290,240 + BLC ≈ 126.4 MB.
  float* W = (float*)d_ws;
  const size_t BLC = (size_t)4 * 4096 * 192;       // 3,145,728
  float*   xn   = W;                               // 1 BLC (LN out; later glu spans xn+xs)
  float*   xs   = W + BLC;                         // 1 BLC (conv input; Hc; sgout? no: glu hi half)
  float*   xc   = W + 2 * BLC;                     // 4 BLC (xc per dir -> outr -> h1 -> sgout)
  ushortT* zbf  = (ushortT*)(W + 6 * BLC);         // 4*BLC bf16 (z -> g in place)
  float*   dbl  = W + 8 * BLC;                     // 2,883,584 fp32
  ushortT* wbf  = (ushortT*)(W + 8 * BLC + 2883584);  // 813,312 bf16 weights
  float*   Pc   = W + 8 * BLC + 2883584 + 406656;  // 1 BLC (chunk carries -> fused)
  float*   Hc   = xs;
  float*   fused = Pc;
  float*   outl = xc + BLC;
  float*   h1   = xc;                              // [16384][768]
  float*   glu  = xn;                              // [16384][384] spans xn..xs
  float*   sgout = xc;                             // reuse after dwglu

  auto gs = [](size_t n) { size_t g = (n + 255) / 256; return (int)(g > 8192 ? 8192 : g); };
  const int nBLC = (int)BLC;

  // 0. weights -> bf16 [N][K]
  prep_w<<<(813312 + 255) / 256, 256, 0, stream>>>(r_in_w, r_xproj_w, r_out_w, l_in_w,
                                                   l_xproj_w, l_out_w, c1_w, c2_w, wbf);
  // 1. LayerNorm
  ln_kernel<<<dim3(256), dim3(256), 0, stream>>>(x, ln_g, ln_b, xn);

  // 2. Region branch
  const ushortT* w_in  = wbf;            // [384][192] x4, stride 73728
  const ushortT* w_xp  = wbf + 294912;   // [44][192]  x4, stride 8448
  const ushortT* w_out = wbf + 328704;   // [192][192] x4, stride 36864
  for (int d = 0; d < 4; ++d) {
    const ushortT* wi = w_in + (size_t)d * 73728;
    // xs = xn(perm) @ in_w[:, :192]
    switch (d) {
      case 0: gemm_mfma<0,0,0,64><<<768, 256, 0, stream>>>(xn, wi, nullptr, xs, 16384, 192, 192, 3); break;
      case 1: gemm_mfma<1,0,0,64><<<768, 256, 0, stream>>>(xn, wi, nullptr, xs, 16384, 192, 192, 3); break;
      case 2: gemm_mfma<2,0,0,64><<<768, 256, 0, stream>>>(xn, wi, nullptr, xs, 16384, 192, 192, 3); break;
      case 3: gemm_mfma<3,0,0,64><<<768, 256, 0, stream>>>(xn, wi, nullptr, xs, 16384, 192, 192, 3); break;
    }
    // z_bf[d] = xn(perm) @ in_w[:, 192:]
    ushortT* zd = zbf + (size_t)d * BLC;
    const ushortT* wz = wi + 192 * 192;
    switch (d) {
      case 0: gemm_mfma<0,0,1,64><<<768, 256, 0, stream>>>(xn, wz, nullptr, zd, 16384, 192, 192, 3); break;
      case 1: gemm_mfma<1,0,1,64><<<768, 256, 0, stream>>>(xn, wz, nullptr, zd, 16384, 192, 192, 3); break;
      case 2: gemm_mfma<2,0,1,64><<<768, 256, 0, stream>>>(xn, wz, nullptr, zd, 16384, 192, 192, 3); break;
      case 3: gemm_mfma<3,0,1,64><<<768, 256, 0, stream>>>(xn, wz, nullptr, zd, 16384, 192, 192, 3); break;
    }
    conv_region_k<<<gs(BLC), 256, 0, stream>>>(xs, r_conv_w + (size_t)d * 768,
                                               r_conv_b + (size_t)d * 192, xc + d * BLC, nBLC);
    gemm_mfma<0,0,0,64><<<256, 256, 0, stream>>>(xc + d * BLC, w_xp + (size_t)d * 8448, nullptr,
                                                 dbl + (size_t)d * 720896, 16384, 44, 192, 1);
  }
  scan_chunkA<<<3072, 64, 0, stream>>>(xc, dbl, r_dt_w, r_dt_b, r_Alog, Pc, Hc);
  scan_combine<<<192, 256, 0, stream>>>(Pc, Hc);
  scan_chunkC<<<3072, 64, 0, stream>>>(xc, dbl, zbf, Pc, r_dt_w, r_dt_b, r_Alog, r_D);
  for (int d = 0; d < 4; ++d)
    gemm_mfma<0,1,0,64><<<768, 256, 0, stream>>>(zbf + (size_t)d * BLC, w_out + (size_t)d * 36864,
                                                 nullptr, xc + d * BLC, 16384, 192, 192, 3);
  combine_k<<<gs(BLC), 256, 0, stream>>>(xc, scale_mod, fused, nBLC);

  // 3. Local windowed branch
  const ushortT* wl_in  = wbf + 476160;  // [384][192]
  const ushortT* wl_xp  = wbf + 549888;  // [28][192]
  const ushortT* wl_out = wbf + 555264;  // [192][192]
  gemm_mfma<4,0,0,64><<<768, 256, 0, stream>>>(xn, wl_in, nullptr, xs, 16384, 192, 192, 3);
  gemm_mfma<4,0,1,64><<<768, 256, 0, stream>>>(xn, wl_in + 192 * 192, nullptr, zbf, 16384, 192, 192, 3);
  conv_local_k<<<gs(BLC), 256, 0, stream>>>(xs, l_conv_w, l_conv_b, xc, nBLC);
  gemm_mfma<0,0,0,64><<<256, 256, 0, stream>>>(xc, wl_xp, nullptr, dbl, 16384, 28, 192, 1);
  scan_local<<<768, 64, 0, stream>>>(xc, dbl, zbf, l_dt_w, l_dt_b, l_Alog, l_D);
  gemm_mfma<0,1,0,64><<<768, 256, 0, stream>>>(zbf, wl_out, nullptr, outl, 16384, 192, 192, 3);
  fuse_k<<<gs(BLC), 256, 0, stream>>>(fused, outl, nBLC);

  // 4. SGFN + final residual
  const ushortT* w_c1 = wbf + 592128;    // [768][192]
  const ushortT* w_c2 = wbf + 739584;    // [192][384]
  gemm_mfma<0,0,0,128><<<1536, 256, 0, stream>>>(fused, w_c1, c1_b, h1, 16384, 768, 192, 12);
  dwglu_k<<<gs((size_t)16384 * 384), 256, 0, stream>>>(h1, dw_w, dw_b, glu, 16384 * 384);
  gemm_mfma<0,0,0,128><<<384, 256, 0, stream>>>(glu, w_c2, c2_b, sgout, 16384, 192, 384, 3);
  final_k<<<gs(BLC), 256, 0, stream>>>(x, fused, sgout, gamma, out, nBLC);
}

// Round 4
// 748.120 us; speedup vs baseline: 6.6026x; 1.0302x over previous
//
#include <hip/hip_runtime.h>

typedef unsigned short ushortT;
typedef unsigned int uintT;
typedef __bf16 bf16x8 __attribute__((ext_vector_type(8)));
typedef short short8v __attribute__((ext_vector_type(8)));
typedef float f32x4 __attribute__((ext_vector_type(4)));
typedef float float4v __attribute__((ext_vector_type(4)));

#define DEV __device__ __forceinline__

DEV float sigmoidf_(float x) { return 1.f / (1.f + __expf(-x)); }
DEV float siluf_(float x)    { return x * sigmoidf_(x); }
DEV float softplusf_(float x){ return fmaxf(x, 0.f) + log1pf(__expf(-fabsf(x))); }

DEV ushortT f2bf(float f) {
  union { float f; uintT u; } x; x.f = f;
  uintT u = x.u + 0x7fffu + ((x.u >> 16) & 1u);
  return (ushortT)(u >> 16);
}
DEV float bf2f(ushortT h) {
  union { uintT u; float f; } x; x.u = ((uintT)h) << 16;
  return x.f;
}

// ---------------- LayerNorm over C (NCHW in -> NHWC out, fp32) ----------------
__global__ __launch_bounds__(256)
void ln_kernel(const float* __restrict__ x, const float* __restrict__ g,
               const float* __restrict__ b, float* __restrict__ xn) {
  const int C = 192, HW = 4096;
  __shared__ float tile[64][193];
  __shared__ float red[2][4][64];
  __shared__ float mean_s[64], rstd_s[64];
  int bb = blockIdx.x >> 6;
  int p0 = (blockIdx.x & 63) << 6;
  int tid = threadIdx.x;
  int p = tid & 63, c4 = tid >> 6;
  for (int c = c4; c < C; c += 4)
    tile[p][c] = x[((size_t)(bb * C + c)) * HW + p0 + p];
  __syncthreads();
  float s = 0.f, s2 = 0.f;
  for (int c = c4 * 48; c < c4 * 48 + 48; ++c) { float v = tile[p][c]; s += v; s2 += v * v; }
  red[0][c4][p] = s; red[1][c4][p] = s2;
  __syncthreads();
  if (c4 == 0) {
    float ss = red[0][0][p] + red[0][1][p] + red[0][2][p] + red[0][3][p];
    float qq = red[1][0][p] + red[1][1][p] + red[1][2][p] + red[1][3][p];
    float m = ss * (1.f / 192.f);
    float var = qq * (1.f / 192.f) - m * m;
    mean_s[p] = m;
    rstd_s[p] = rsqrtf(var + 1e-5f);
  }
  __syncthreads();
  for (int e = tid; e < 64 * 192; e += 256) {
    int pp = e / 192, c = e % 192;
    xn[((size_t)bb * HW + p0 + pp) * C + c] =
        (tile[pp][c] - mean_s[pp]) * rstd_s[pp] * g[c] + b[c];
  }
}

// ---------------- weight prep: cast/transpose all GEMM B operands to bf16 [N][K] ----------------
__global__ __launch_bounds__(256)
void prep_w(const float* __restrict__ r_in_w, const float* __restrict__ r_xproj_w,
            const float* __restrict__ r_out_w, const float* __restrict__ l_in_w,
            const float* __restrict__ l_xproj_w, const float* __restrict__ l_out_w,
            const float* __restrict__ c1_w, const float* __restrict__ c2_w,
            ushortT* __restrict__ wbf) {
  int i = blockIdx.x * 256 + threadIdx.x;
  if (i >= 813312) return;
  float v;
  if (i < 294912) {                 // r_in_w [192][384] -> [384][192] x4
    int d = i / 73728, j = i % 73728, n = j / 192, k = j % 192;
    v = r_in_w[(size_t)d * 73728 + k * 384 + n];
  } else if (i < 328704) {          // r_xproj [192][44] -> [44][192] x4
    int j = i - 294912; int d = j / 8448, jj = j % 8448, n = jj / 192, k = jj % 192;
    v = r_xproj_w[(size_t)d * 8448 + k * 44 + n];
  } else if (i < 476160) {          // r_out [192][192] -> [192][192]^T x4
    int j = i - 328704; int d = j / 36864, jj = j % 36864, n = jj / 192, k = jj % 192;
    v = r_out_w[(size_t)d * 36864 + k * 192 + n];
  } else if (i < 549888) {          // l_in_w [192][384] -> [384][192]
    int j = i - 476160; int n = j / 192, k = j % 192;
    v = l_in_w[k * 384 + n];
  } else if (i < 555264) {          // l_xproj [192][28] -> [28][192]
    int j = i - 549888; int n = j / 192, k = j % 192;
    v = l_xproj_w[k * 28 + n];
  } else if (i < 592128) {          // l_out [192][192]^T
    int j = i - 555264; int n = j / 192, k = j % 192;
    v = l_out_w[k * 192 + n];
  } else if (i < 739584) {          // c1_w [768][192] already [N][K]
    v = c1_w[i - 592128];
  } else {                          // c2_w [192][384] already [N][K]
    v = c2_w[i - 739584];
  }
  wbf[i] = f2bf(v);
}

// ---------------- A-row permutations (gather fused into GEMM) ----------------
template <int PERM> DEV int permrow(int m) {
  if (PERM == 0) return m;
  int b = m >> 12, l = m & 4095;
  if (PERM == 1) return (b << 12) | (4095 - l);
  if (PERM == 2) return (b << 12) | (((l & 63) << 6) | (l >> 6));
  if (PERM == 3) { int s = 4095 - l; return (b << 12) | (((s & 63) << 6) | (s >> 6)); }
  // PERM==4: 8x8 window order
  int ih = (m >> 9) & 7, iw = (m >> 6) & 7, p = (m >> 3) & 7, q = m & 7;
  return (b << 12) | ((((ih << 3) | p) << 6) | ((iw << 3) | q));
}

// ---------------- MFMA bf16 GEMM: C = A[M,K] * B^T(bf16 [N][K]) + bias ----------------
// EPI 0: fp32 -> C1[row*N+col]; EPI 1: bf16 -> C1[row*N+col];
// EPI 2: split (N=384): col<192 -> bf16 C1[row*192+col], col>=192 -> bf16 C2[row*192+col-192]
template <int PERM, int ABF16, int EPI, int BM>
__global__ __launch_bounds__(256)
void gemm_mfma(const void* __restrict__ Ap, const ushortT* __restrict__ Bw,
               const float* __restrict__ bias, void* __restrict__ C1,
               void* __restrict__ C2, int M, int N, int K, int nbn) {
  __shared__ __align__(16) ushortT As[BM * 192];
  __shared__ __align__(16) ushortT Bs[64 * 192];
  int nwg = gridDim.x;
  int bid = blockIdx.x;
  int q = nwg >> 3, r = nwg & 7, xq = bid & 7, o = bid >> 3;
  int wg = (xq < r ? xq * (q + 1) : r * (q + 1) + (xq - r) * q) + o;
  int bn = (wg % nbn) * 64;
  int bm = (wg / nbn) * BM;
  int tid = threadIdx.x;
  int lane = tid & 63, w = tid >> 6;
  constexpr int MF = BM / 32;
  int wm = (w >> 1) * (MF * 16), wn = (w & 1) * 32;
  f32x4 acc[MF][2] = {};

  for (int k0 = 0; k0 < K; k0 += 192) {
    for (int ci = tid; ci < BM * 24; ci += 256) {
      int row = ci / 24, s = ci - row * 24;
      int srow = permrow<PERM>(bm + row);
      int sw = (s & ~7) | ((s ^ row) & 7);
      short8v v;
      if (ABF16) {
        v = *(const short8v*)((const ushortT*)Ap + (size_t)srow * K + k0 + s * 8);
      } else {
        const float* af = (const float*)Ap + (size_t)srow * K + k0 + s * 8;
        float4v f0 = *(const float4v*)af;
        float4v f1 = *(const float4v*)(af + 4);
#pragma unroll
        for (int j = 0; j < 4; ++j) v[j] = (short)f2bf(f0[j]);
#pragma unroll
        for (int j = 0; j < 4; ++j) v[4 + j] = (short)f2bf(f1[j]);
      }
      *(short8v*)&As[row * 192 + sw * 8] = v;
    }
    for (int ci = tid; ci < 64 * 24; ci += 256) {
      int row = ci / 24, s = ci - row * 24;
      int n = bn + row;
      int sw = (s & ~7) | ((s ^ row) & 7);
      short8v v = {};
      if (n < N) v = *(const short8v*)(Bw + (size_t)n * K + k0 + s * 8);
      *(short8v*)&Bs[row * 192 + sw * 8] = v;
    }
    __syncthreads();
#pragma unroll
    for (int kk = 0; kk < 6; ++kk) {
      int sbase = kk * 4 + (lane >> 4);
      bf16x8 a[MF], bfr[2];
#pragma unroll
      for (int mf = 0; mf < MF; ++mf) {
        int rw = wm + mf * 16 + (lane & 15);
        int sw = (sbase & ~7) | ((sbase ^ rw) & 7);
        a[mf] = __builtin_bit_cast(bf16x8, *(const short8v*)&As[rw * 192 + sw * 8]);
      }
#pragma unroll
      for (int nf = 0; nf < 2; ++nf) {
        int rw = wn + nf * 16 + (lane & 15);
        int sw = (sbase & ~7) | ((sbase ^ rw) & 7);
        bfr[nf] = __builtin_bit_cast(bf16x8, *(const short8v*)&Bs[rw * 192 + sw * 8]);
      }
#pragma unroll
      for (int mf = 0; mf < MF; ++mf)
#pragma unroll
        for (int nf = 0; nf < 2; ++nf)
          acc[mf][nf] = __builtin_amdgcn_mfma_f32_16x16x32_bf16(a[mf], bfr[nf], acc[mf][nf], 0, 0, 0);
    }
    __syncthreads();
  }
#pragma unroll
  for (int mf = 0; mf < MF; ++mf)
#pragma unroll
    for (int nf = 0; nf < 2; ++nf)
#pragma unroll
      for (int j = 0; j < 4; ++j) {
        int rowg = bm + wm + mf * 16 + ((lane >> 4) << 2) + j;
        int colg = bn + wn + nf * 16 + (lane & 15);
        if (colg < N) {
          float v2 = acc[mf][nf][j] + (bias ? bias[colg] : 0.f);
          if (EPI == 0)      ((float*)C1)[(size_t)rowg * N + colg] = v2;
          else if (EPI == 1) ((ushortT*)C1)[(size_t)rowg * N + colg] = f2bf(v2);
          else {             // split N=384
            if (colg < 192) ((ushortT*)C1)[(size_t)rowg * 192 + colg] = f2bf(v2);
            else            ((ushortT*)C2)[(size_t)rowg * 192 + colg - 192] = f2bf(v2);
          }
        }
      }
}

// ---------------- causal depthwise conv K=4 + silu (region, bf16 io) ----------------
__global__ void conv_region_k(const ushortT* __restrict__ xs, const float* __restrict__ w,
                              const float* __restrict__ cb, ushortT* __restrict__ out, int n) {
  for (int i = blockIdx.x * blockDim.x + threadIdx.x; i < n; i += gridDim.x * blockDim.x) {
    int c = i % 192;
    int row = i / 192;
    int l = row & 4095;
    float acc = cb[c];
#pragma unroll
    for (int k = 0; k < 4; ++k) {
      int ls = l + k - 3;
      if (ls >= 0) acc = fmaf(bf2f(xs[(size_t)(row + k - 3) * 192 + c]), w[c * 4 + k], acc);
    }
    out[i] = f2bf(siluf_(acc));
  }
}

// ---------------- causal depthwise conv K=2 + silu (local, bf16 io) ----------------
__global__ void conv_local_k(const ushortT* __restrict__ xs, const float* __restrict__ w,
                             const float* __restrict__ cb, ushortT* __restrict__ out, int n) {
  for (int i = blockIdx.x * blockDim.x + threadIdx.x; i < n; i += gridDim.x * blockDim.x) {
    int c = i % 192;
    int row = i / 192;
    int t = row & 63;
    float acc = fmaf(bf2f(xs[(size_t)row * 192 + c]), w[c * 2 + 1], cb[c]);
    if (t > 0) acc = fmaf(bf2f(xs[(size_t)(row - 1) * 192 + c]), w[c * 2 + 0], acc);
    out[i] = f2bf(siluf_(acc));
  }
}

// ======== region scan, chunked parallel: 128 chunks of 32, N=16 ========
__global__ __launch_bounds__(192)
void scanA_r(const ushortT* __restrict__ xc, const float* __restrict__ dbl,
             const float* __restrict__ dt_w, const float* __restrict__ dt_b,
             const float* __restrict__ Alog,
             float* __restrict__ Pc, float* __restrict__ Hc) {
  int blk = blockIdx.x;              // seq*128 + chunk
  int chunk = blk & 127, seq = blk >> 7, dir = seq >> 2;
  int c = threadIdx.x;
  float A[16], P[16], H[16], wdt[12];
#pragma unroll
  for (int nn = 0; nn < 16; ++nn) {
    A[nn] = -__expf(Alog[(size_t)(dir * 192 + c) * 16 + nn]);
    P[nn] = 1.f; H[nn] = 0.f;
  }
#pragma unroll
  for (int r = 0; r < 12; ++r) wdt[r] = dt_w[(size_t)(dir * 12 + r) * 192 + c];
  float bdt = dt_b[dir * 192 + c];
  size_t rowbase = (size_t)seq * 4096 + chunk * 32;
  for (int t = 0; t < 32; ++t) {
    size_t row = rowbase + t;
    const float* dd = dbl + row * 44;
    float dtr = bdt;
#pragma unroll
    for (int r = 0; r < 12; ++r) dtr = fmaf(dd[r], wdt[r], dtr);
    float dtv = softplusf_(dtr);
    float dx = dtv * bf2f(xc[row * 192 + c]);
#pragma unroll
    for (int nn = 0; nn < 16; ++nn) {
      float a = __expf(dtv * A[nn]);
      P[nn] *= a;
      H[nn] = fmaf(a, H[nn], dx * dd[12 + nn]);
    }
  }
  size_t ob = ((size_t)(seq * 128 + chunk) * 192 + c) * 16;
#pragma unroll
  for (int nn = 0; nn < 16; ++nn) { Pc[ob + nn] = P[nn]; Hc[ob + nn] = H[nn]; }
}

__global__ __launch_bounds__(256)
void combine_r(float* __restrict__ Pc, const float* __restrict__ Hc) {
  int gid = blockIdx.x * 256 + threadIdx.x;   // 16*192*16 = 49152
  int nn = gid & 15;
  int c = (gid >> 4) % 192;
  int seq = gid / (192 * 16);
  float h = 0.f;
  for (int ch = 0; ch < 128; ++ch) {
    size_t idx = (((size_t)(seq * 128 + ch) * 192 + c) << 4) + nn;
    float nh = fmaf(Pc[idx], h, Hc[idx]);
    Pc[idx] = h;
    h = nh;
  }
}

__global__ __launch_bounds__(192)
void scanC_r(const ushortT* __restrict__ xc, const float* __restrict__ dbl,
             ushortT* __restrict__ zg, const float* __restrict__ Pc,
             const float* __restrict__ dt_w, const float* __restrict__ dt_b,
             const float* __restrict__ Alog, const float* __restrict__ Dskip) {
  int blk = blockIdx.x;
  int chunk = blk & 127, seq = blk >> 7, dir = seq >> 2;
  int c = threadIdx.x;
  float A[16], h[16], wdt[12];
  size_t ob = ((size_t)(seq * 128 + chunk) * 192 + c) * 16;
#pragma unroll
  for (int nn = 0; nn < 16; ++nn) {
    A[nn] = -__expf(Alog[(size_t)(dir * 192 + c) * 16 + nn]);
    h[nn] = Pc[ob + nn];
  }
#pragma unroll
  for (int r = 0; r < 12; ++r) wdt[r] = dt_w[(size_t)(dir * 12 + r) * 192 + c];
  float bdt = dt_b[dir * 192 + c];
  float Dv  = Dskip[dir * 192 + c];
  size_t rowbase = (size_t)seq * 4096 + chunk * 32;
  for (int t = 0; t < 32; ++t) {
    size_t row = rowbase + t;
    const float* dd = dbl + row * 44;
    float dtr = bdt;
#pragma unroll
    for (int r = 0; r < 12; ++r) dtr = fmaf(dd[r], wdt[r], dtr);
    float dtv = softplusf_(dtr);
    float xv  = bf2f(xc[row * 192 + c]);
    float dx  = dtv * xv;
    float y = 0.f;
#pragma unroll
    for (int nn = 0; nn < 16; ++nn) {
      float a = __expf(dtv * A[nn]);
      h[nn] = fmaf(a, h[nn], dx * dd[12 + nn]);
      y = fmaf(h[nn], dd[28 + nn], y);
    }
    y = fmaf(xv, Dv, y);
    float zv = bf2f(zg[row * 192 + c]);
    zg[row * 192 + c] = f2bf(y * siluf_(zv));
  }
}

// ======== local scan, chunked: 256 windows, 4 chunks of 16, N=8 ========
__global__ __launch_bounds__(192)
void scanA_l(const ushortT* __restrict__ xc, const float* __restrict__ dbl,
             const float* __restrict__ dt_w, const float* __restrict__ dt_b,
             const float* __restrict__ Alog,
             float* __restrict__ Pc, float* __restrict__ Hc) {
  int blk = blockIdx.x;              // win*4 + chunk
  int chunk = blk & 3, win = blk >> 2;
  int c = threadIdx.x;
  float A[8], P[8], H[8], wdt[12];
#pragma unroll
  for (int nn = 0; nn < 8; ++nn) {
    A[nn] = -__expf(Alog[(size_t)c * 8 + nn]);
    P[nn] = 1.f; H[nn] = 0.f;
  }
#pragma unroll
  for (int r = 0; r < 12; ++r) wdt[r] = dt_w[(size_t)r * 192 + c];
  float bdt = dt_b[c];
  size_t rowbase = (size_t)win * 64 + chunk * 16;
  for (int t = 0; t < 16; ++t) {
    size_t row = rowbase + t;
    const float* dd = dbl + row * 28;
    float dtr = bdt;
#pragma unroll
    for (int r = 0; r < 12; ++r) dtr = fmaf(dd[r], wdt[r], dtr);
    float dtv = softplusf_(dtr);
    float dx = dtv * bf2f(xc[row * 192 + c]);
#pragma unroll
    for (int nn = 0; nn < 8; ++nn) {
      float a = __expf(dtv * A[nn]);
      P[nn] *= a;
      H[nn] = fmaf(a, H[nn], dx * dd[12 + nn]);
    }
  }
  size_t ob = ((size_t)(win * 4 + chunk) * 192 + c) * 8;
#pragma unroll
  for (int nn = 0; nn < 8; ++nn) { Pc[ob + nn] = P[nn]; Hc[ob + nn] = H[nn]; }
}

__global__ __launch_bounds__(256)
void combine_l(float* __restrict__ Pc, const float* __restrict__ Hc) {
  int gid = blockIdx.x * 256 + threadIdx.x;   // 256*192*8 = 393216
  int nn = gid & 7;
  int c = (gid >> 3) % 192;
  int win = gid / (192 * 8);
  float h = 0.f;
#pragma unroll
  for (int ch = 0; ch < 4; ++ch) {
    size_t idx = (((size_t)(win * 4 + ch) * 192 + c) << 3) + nn;
    float nh = fmaf(Pc[idx], h, Hc[idx]);
    Pc[idx] = h;
    h = nh;
  }
}

__global__ __launch_bounds__(192)
void scanC_l(const ushortT* __restrict__ xc, const float* __restrict__ dbl,
             ushortT* __restrict__ zg, const float* __restrict__ Pc,
             const float* __restrict__ dt_w, const float* __restrict__ dt_b,
             const float* __restrict__ Alog, const float* __restrict__ Dskip) {
  int blk = blockIdx.x;
  int chunk = blk & 3, win = blk >> 2;
  int c = threadIdx.x;
  float A[8], h[8], wdt[12];
  size_t ob = ((size_t)(win * 4 + chunk) * 192 + c) * 8;
#pragma unroll
  for (int nn = 0; nn < 8; ++nn) {
    A[nn] = -__expf(Alog[(size_t)c * 8 + nn]);
    h[nn] = Pc[ob + nn];
  }
#pragma unroll
  for (int r = 0; r < 12; ++r) wdt[r] = dt_w[(size_t)r * 192 + c];
  float bdt = dt_b[c];
  float Dv  = Dskip[c];
  size_t rowbase = (size_t)win * 64 + chunk * 16;
  for (int t = 0; t < 16; ++t) {
    size_t row = rowbase + t;
    const float* dd = dbl + row * 28;
    float dtr = bdt;
#pragma unroll
    for (int r = 0; r < 12; ++r) dtr = fmaf(dd[r], wdt[r], dtr);
    float dtv = softplusf_(dtr);
    float xv  = bf2f(xc[row * 192 + c]);
    float dx  = dtv * xv;
    float y = 0.f;
#pragma unroll
    for (int nn = 0; nn < 8; ++nn) {
      float a = __expf(dtv * A[nn]);
      h[nn] = fmaf(a, h[nn], dx * dd[12 + nn]);
      y = fmaf(h[nn], dd[20 + nn], y);
    }
    y = fmaf(xv, Dv, y);
    float zv = bf2f(zg[row * 192 + c]);
    zg[row * 192 + c] = f2bf(y * siluf_(zv));
  }
}

// ---------------- combine 4 directional outputs (bf16 in, fp32 out) ----------------
__global__ void combine_k(const ushortT* __restrict__ outr, const float* __restrict__ scale_mod,
                          float* __restrict__ reg, int n) {
  const size_t BLC = (size_t)4 * 4096 * 192;
  float sc = 0.25f * scale_mod[0];
  for (int i = blockIdx.x * blockDim.x + threadIdx.x; i < n; i += gridDim.x * blockDim.x) {
    int c = i % 192;
    int l = (i / 192) & 4095;
    int b = i / (192 * 4096);
    int hh = l >> 6, ww = l & 63;
    int lv = (ww << 6) | hh;
    size_t rb = (size_t)b * 4096;
    float v = bf2f(outr[((rb + l) * 192) + c])
            + bf2f(outr[BLC + ((rb + (4095 - l)) * 192) + c])
            + bf2f(outr[2 * BLC + ((rb + lv) * 192) + c])
            + bf2f(outr[3 * BLC + ((rb + (4095 - lv)) * 192) + c]);
    reg[i] = v * sc;
  }
}

// ---------------- fused += local out (un-window, bf16 in) ----------------
__global__ void fuse_k(float* __restrict__ fused, const ushortT* __restrict__ outl, int n) {
  for (int i = blockIdx.x * blockDim.x + threadIdx.x; i < n; i += gridDim.x * blockDim.x) {
    int c = i % 192;
    int l = (i / 192) & 4095;
    int b = i / (192 * 4096);
    int hh = l >> 6, ww = l & 63;
    int win = ((b * 8 + (hh >> 3)) * 8) + (ww >> 3);
    int t = ((hh & 7) << 3) | (ww & 7);
    fused[i] += bf2f(outl[((size_t)win * 64 + t) * 192 + c]);
  }
}

// ---------------- depthwise 3x3 (SAME) + GLU ----------------
__global__ void dwglu_k(const float* __restrict__ h1, const float* __restrict__ dw_w,
                        const float* __restrict__ dw_b, float* __restrict__ glu, int n) {
  for (int i = blockIdx.x * blockDim.x + threadIdx.x; i < n; i += gridDim.x * blockDim.x) {
    int m = i % 384;
    int pix = i / 384;
    int p = pix & 4095, b = pix >> 12;
    int y = p >> 6, xx0 = p & 63;
    float a1 = dw_b[m], a2 = dw_b[m + 384];
#pragma unroll
    for (int dy = 0; dy < 3; ++dy) {
      int yy = y + dy - 1;
      if (yy < 0 || yy >= 64) continue;
#pragma unroll
      for (int dx = 0; dx < 3; ++dx) {
        int xx = xx0 + dx - 1;
        if (xx < 0 || xx >= 64) continue;
        const float* hp = h1 + ((size_t)(b * 4096) + yy * 64 + xx) * 768;
        a1 = fmaf(hp[m],       dw_w[(size_t)m * 9 + dy * 3 + dx],         a1);
        a2 = fmaf(hp[m + 384], dw_w[(size_t)(m + 384) * 9 + dy * 3 + dx], a2);
      }
    }
    glu[i] = a1 * sigmoidf_(a2);
  }
}

// ---------------- final: out = x + gamma*(fused + sgout), back to NCHW ----------------
__global__ void final_k(const float* __restrict__ x, const float* __restrict__ fused,
                        const float* __restrict__ sgout, const float* __restrict__ gamma,
                        float* __restrict__ out, int n) {
  float gm = gamma[0];
  for (int i = blockIdx.x * blockDim.x + threadIdx.x; i < n; i += gridDim.x * blockDim.x) {
    int p = i & 4095;
    int ch = (i >> 12) % 192;
    int b = i / (192 * 4096);
    size_t idx = ((size_t)(b * 4096) + p) * 192 + ch;
    out[i] = fmaf(gm, fused[idx] + sgout[idx], x[i]);
  }
}

extern "C" void kernel_launch(void* const* d_in, const int* in_sizes, int n_in,
                              void* d_out, int out_size, void* d_ws, size_t ws_size,
                              hipStream_t stream) {
  const float* x         = (const float*)d_in[0];
  const float* r_conv_w  = (const float*)d_in[2];
  const float* r_conv_b  = (const float*)d_in[3];
  const float* r_dt_w    = (const float*)d_in[5];
  const float* r_dt_b    = (const float*)d_in[6];
  const float* r_Alog    = (const float*)d_in[7];
  const float* r_D       = (const float*)d_in[8];
  const float* scale_mod = (const float*)d_in[10];
  const float* l_conv_w  = (const float*)d_in[12];
  const float* l_conv_b  = (const float*)d_in[13];
  const float* l_dt_w    = (const float*)d_in[15];
  const float* l_dt_b    = (const float*)d_in[16];
  const float* l_Alog    = (const float*)d_in[17];
  const float* l_D       = (const float*)d_in[18];
  const float* ln_g      = (const float*)d_in[20];
  const float* ln_b      = (const float*)d_in[21];
  const float* c1_b      = (const float*)d_in[23];
  const float* dw_w      = (const float*)d_in[24];
  const float* dw_b      = (const float*)d_in[25];
  const float* c2_b      = (const float*)d_in[27];
  const float* gamma     = (const float*)d_in[28];
  float* out = (float*)d_out;

  // ---- workspace arena (float offsets; BLC = 3,145,728; total 132.7 MB) ----
  float* W = (float*)d_ws;
  const size_t BLC = (size_t)4 * 4096 * 192;
  float*   xn    = W;                                  // [16384][192] fp32
  ushortT* xcbf  = (ushortT*)(W + BLC);                // 4*BLC bf16 (xc per dir; local xc)
  ushortT* outr  = xcbf;                               // bf16 outr/outl (after xc dead)
  ushortT* zbf   = (ushortT*)(W + 3 * BLC);            // 4*BLC bf16 (z -> g)
  ushortT* xsbf  = (ushortT*)(W + 5 * BLC);            // BLC bf16 (conv input, transient)
  float*   dbl   = W + 5 * BLC + BLC / 2;              // region 4*720896; local 458752 fp32
  float*   Pc    = W + 5 * BLC + BLC / 2 + 2883584;    // 6,291,456 fp32 (region P / h_in)
  float*   Hc    = Pc + 6291456;                       // 6,291,456 fp32
  float*   fused = Pc;                                 // BLC fp32 (after region scans done)
  float*   Pl    = Hc;                                 // local carries (after region done)
  float*   Hl    = Hc + 1572864;
  float*   h1    = W;                                  // [16384][768] fp32 (SGFN)
  float*   glu   = W + 4 * BLC;                        // [16384][384] fp32
  float*   sgout = Hc;                                 // BLC fp32
  ushortT* wbf   = (ushortT*)(Hc + 6291456);           // 813,312 bf16 weights

  auto gs = [](size_t n) { size_t g = (n + 255) / 256; return (int)(g > 8192 ? 8192 : g); };
  const int nBLC = (int)BLC;

  // 0. weights -> bf16 [N][K]
  prep_w<<<(813312 + 255) / 256, 256, 0, stream>>>(d_in[1] ? (const float*)d_in[1] : nullptr,
                                                   (const float*)d_in[4], (const float*)d_in[9],
                                                   (const float*)d_in[11], (const float*)d_in[14],
                                                   (const float*)d_in[19], (const float*)d_in[22],
                                                   (const float*)d_in[26], wbf);
  // 1. LayerNorm
  ln_kernel<<<dim3(256), dim3(256), 0, stream>>>(x, ln_g, ln_b, xn);

  // 2. Region branch
  const ushortT* w_in  = wbf;            // [384][192] x4
  const ushortT* w_xp  = wbf + 294912;   // [44][192]  x4
  const ushortT* w_out = wbf + 328704;   // [192][192] x4
  for (int d = 0; d < 4; ++d) {
    const ushortT* wi = w_in + (size_t)d * 73728;
    ushortT* zd = zbf + (size_t)d * BLC;
    switch (d) {   // merged xs+z GEMM, N=384, split epilogue
      case 0: gemm_mfma<0,0,2,64><<<1536, 256, 0, stream>>>(xn, wi, nullptr, xsbf, zd, 16384, 384, 192, 6); break;
      case 1: gemm_mfma<1,0,2,64><<<1536, 256, 0, stream>>>(xn, wi, nullptr, xsbf, zd, 16384, 384, 192, 6); break;
      case 2: gemm_mfma<2,0,2,64><<<1536, 256, 0, stream>>>(xn, wi, nullptr, xsbf, zd, 16384, 384, 192, 6); break;
      case 3: gemm_mfma<3,0,2,64><<<1536, 256, 0, stream>>>(xn, wi, nullptr, xsbf, zd, 16384, 384, 192, 6); break;
    }
    conv_region_k<<<gs(BLC), 256, 0, stream>>>(xsbf, r_conv_w + (size_t)d * 768,
                                               r_conv_b + (size_t)d * 192, xcbf + (size_t)d * BLC, nBLC);
    gemm_mfma<0,1,0,64><<<256, 256, 0, stream>>>(xcbf + (size_t)d * BLC, w_xp + (size_t)d * 8448,
                                                 nullptr, dbl + (size_t)d * 720896, nullptr,
                                                 16384, 44, 192, 1);
  }
  scanA_r<<<2048, 192, 0, stream>>>(xcbf, dbl, r_dt_w, r_dt_b, r_Alog, Pc, Hc);
  combine_r<<<192, 256, 0, stream>>>(Pc, Hc);
  scanC_r<<<2048, 192, 0, stream>>>(xcbf, dbl, zbf, Pc, r_dt_w, r_dt_b, r_Alog, r_D);
  for (int d = 0; d < 4; ++d)
    gemm_mfma<0,1,1,64><<<768, 256, 0, stream>>>(zbf + (size_t)d * BLC, w_out + (size_t)d * 36864,
                                                 nullptr, outr + (size_t)d * BLC, nullptr,
                                                 16384, 192, 192, 3);
  combine_k<<<gs(BLC), 256, 0, stream>>>(outr, scale_mod, fused, nBLC);

  // 3. Local windowed branch
  const ushortT* wl_in  = wbf + 476160;  // [384][192]
  const ushortT* wl_xp  = wbf + 549888;  // [28][192]
  const ushortT* wl_out = wbf + 555264;  // [192][192]
  gemm_mfma<4,0,2,64><<<1536, 256, 0, stream>>>(xn, wl_in, nullptr, xsbf, zbf, 16384, 384, 192, 6);
  conv_local_k<<<gs(BLC), 256, 0, stream>>>(xsbf, l_conv_w, l_conv_b, xcbf, nBLC);
  gemm_mfma<0,1,0,64><<<256, 256, 0, stream>>>(xcbf, wl_xp, nullptr, dbl, nullptr, 16384, 28, 192, 1);
  scanA_l<<<1024, 192, 0, stream>>>(xcbf, dbl, l_dt_w, l_dt_b, l_Alog, Pl, Hl);
  combine_l<<<1536, 256, 0, stream>>>(Pl, Hl);
  scanC_l<<<1024, 192, 0, stream>>>(xcbf, dbl, zbf, Pl, l_dt_w, l_dt_b, l_Alog, l_D);
  gemm_mfma<0,1,1,64><<<768, 256, 0, stream>>>(zbf, wl_out, nullptr, outr, nullptr, 16384, 192, 192, 3);
  fuse_k<<<gs(BLC), 256, 0, stream>>>(fused, outr, nBLC);

  // 4. SGFN + final residual
  const ushortT* w_c1 = wbf + 592128;    // [768][192]
  const ushortT* w_c2 = wbf + 739584;    // [192][384]
  gemm_mfma<0,0,0,128><<<1536, 256, 0, stream>>>(fused, w_c1, c1_b, h1, nullptr, 16384, 768, 192, 12);
  dwglu_k<<<gs((size_t)16384 * 384), 256, 0, stream>>>(h1, dw_w, dw_b, glu, 16384 * 384);
  gemm_mfma<0,0,0,128><<<384, 256, 0, stream>>>(glu, w_c2, c2_b, sgout, nullptr, 16384, 192, 384, 3);
  final_k<<<gs(BLC), 256, 0, stream>>>(x, fused, sgout, gamma, out, nBLC);
}

// Round 5
// 592.272 us; speedup vs baseline: 8.3400x; 1.2631x over previous
//
#include <hip/hip_runtime.h>

typedef unsigned short ushortT;
typedef unsigned int uintT;
typedef __bf16 bf16x8 __attribute__((ext_vector_type(8)));
typedef short short8v __attribute__((ext_vector_type(8)));
typedef float f32x4 __attribute__((ext_vector_type(4)));
typedef float float4v __attribute__((ext_vector_type(4)));

#define DEV __device__ __forceinline__

DEV float sigmoidf_(float x) { return 1.f / (1.f + __expf(-x)); }
DEV float siluf_(float x)    { return x * sigmoidf_(x); }
DEV float softplusf_(float x){ return fmaxf(x, 0.f) + log1pf(__expf(-fabsf(x))); }

DEV ushortT f2bf(float f) {
  union { float f; uintT u; } x; x.f = f;
  uintT u = x.u + 0x7fffu + ((x.u >> 16) & 1u);
  return (ushortT)(u >> 16);
}
DEV float bf2f(ushortT h) {
  union { uintT u; float f; } x; x.u = ((uintT)h) << 16;
  return x.f;
}

// ---------------- LayerNorm over C (NCHW in -> NHWC out, fp32) ----------------
__global__ __launch_bounds__(256)
void ln_kernel(const float* __restrict__ x, const float* __restrict__ g,
               const float* __restrict__ b, float* __restrict__ xn) {
  const int C = 192, HW = 4096;
  __shared__ float tile[64][193];
  __shared__ float red[2][4][64];
  __shared__ float mean_s[64], rstd_s[64];
  int bb = blockIdx.x >> 6;
  int p0 = (blockIdx.x & 63) << 6;
  int tid = threadIdx.x;
  int p = tid & 63, c4 = tid >> 6;
  for (int c = c4; c < C; c += 4)
    tile[p][c] = x[((size_t)(bb * C + c)) * HW + p0 + p];
  __syncthreads();
  float s = 0.f, s2 = 0.f;
  for (int c = c4 * 48; c < c4 * 48 + 48; ++c) { float v = tile[p][c]; s += v; s2 += v * v; }
  red[0][c4][p] = s; red[1][c4][p] = s2;
  __syncthreads();
  if (c4 == 0) {
    float ss = red[0][0][p] + red[0][1][p] + red[0][2][p] + red[0][3][p];
    float qq = red[1][0][p] + red[1][1][p] + red[1][2][p] + red[1][3][p];
    float m = ss * (1.f / 192.f);
    float var = qq * (1.f / 192.f) - m * m;
    mean_s[p] = m;
    rstd_s[p] = rsqrtf(var + 1e-5f);
  }
  __syncthreads();
  for (int e = tid; e < 64 * 192; e += 256) {
    int pp = e / 192, c = e % 192;
    xn[((size_t)bb * HW + p0 + pp) * C + c] =
        (tile[pp][c] - mean_s[pp]) * rstd_s[pp] * g[c] + b[c];
  }
}

// ---------------- weight prep: cast/transpose all GEMM B operands to bf16 [N][K] ----------------
__global__ __launch_bounds__(256)
void prep_w(const float* __restrict__ r_in_w, const float* __restrict__ r_xproj_w,
            const float* __restrict__ r_out_w, const float* __restrict__ l_in_w,
            const float* __restrict__ l_xproj_w, const float* __restrict__ l_out_w,
            const float* __restrict__ c1_w, const float* __restrict__ c2_w,
            ushortT* __restrict__ wbf) {
  int i = blockIdx.x * 256 + threadIdx.x;
  if (i >= 813312) return;
  float v;
  if (i < 294912) {                 // r_in_w [192][384] -> [384][192] x4
    int d = i / 73728, j = i % 73728, n = j / 192, k = j % 192;
    v = r_in_w[(size_t)d * 73728 + k * 384 + n];
  } else if (i < 328704) {          // r_xproj [192][44] -> [44][192] x4
    int j = i - 294912; int d = j / 8448, jj = j % 8448, n = jj / 192, k = jj % 192;
    v = r_xproj_w[(size_t)d * 8448 + k * 44 + n];
  } else if (i < 476160) {          // r_out [192][192]^T x4
    int j = i - 328704; int d = j / 36864, jj = j % 36864, n = jj / 192, k = jj % 192;
    v = r_out_w[(size_t)d * 36864 + k * 192 + n];
  } else if (i < 549888) {          // l_in_w [192][384] -> [384][192]
    int j = i - 476160; int n = j / 192, k = j % 192;
    v = l_in_w[k * 384 + n];
  } else if (i < 555264) {          // l_xproj [192][28] -> [28][192]
    int j = i - 549888; int n = j / 192, k = j % 192;
    v = l_xproj_w[k * 28 + n];
  } else if (i < 592128) {          // l_out [192][192]^T
    int j = i - 555264; int n = j / 192, k = j % 192;
    v = l_out_w[k * 192 + n];
  } else if (i < 739584) {          // c1_w [768][192] already [N][K]
    v = c1_w[i - 592128];
  } else {                          // c2_w [192][384] already [N][K]
    v = c2_w[i - 739584];
  }
  wbf[i] = f2bf(v);
}

// ---------------- conv/dw weight transposes (fp32, channel-contiguous) ----------------
// cwt layout: dwt[9][768] | rcwt[4][4][192] | lcwt[2][192]   (total 10368 floats)
__global__ __launch_bounds__(256)
void prep_cw(const float* __restrict__ dw_w, const float* __restrict__ r_conv_w,
             const float* __restrict__ l_conv_w, float* __restrict__ cwt) {
  int i = blockIdx.x * 256 + threadIdx.x;
  if (i < 6912) {                       // dw_w [768][9] -> dwt[tap][ch]
    int ch = i / 9, tap = i % 9;
    cwt[tap * 768 + ch] = dw_w[i];
  } else if (i < 6912 + 3072) {         // r_conv_w [4][192][4] -> rcwt[d][k][ch]
    int j = i - 6912; int d = j / 768, ch = (j % 768) / 4, k = j & 3;
    cwt[6912 + (d * 4 + k) * 192 + ch] = r_conv_w[j];
  } else if (i < 6912 + 3072 + 384) {   // l_conv_w [192][2] -> lcwt[k][ch]
    int j = i - 6912 - 3072; int ch = j >> 1, k = j & 1;
    cwt[9984 + k * 192 + ch] = l_conv_w[j];
  }
}

// ---------------- A-row permutations (gather fused into GEMM) ----------------
template <int PERM> DEV int permrow(int m) {
  if (PERM == 0) return m;
  int b = m >> 12, l = m & 4095;
  if (PERM == 1) return (b << 12) | (4095 - l);
  if (PERM == 2) return (b << 12) | (((l & 63) << 6) | (l >> 6));
  if (PERM == 3) { int s = 4095 - l; return (b << 12) | (((s & 63) << 6) | (s >> 6)); }
  int ih = (m >> 9) & 7, iw = (m >> 6) & 7, p = (m >> 3) & 7, q = m & 7;
  return (b << 12) | ((((ih << 3) | p) << 6) | ((iw << 3) | q));
}

// ---------------- MFMA bf16 GEMM: C = A[M,K] * B^T(bf16 [N][K]) + bias ----------------
// EPI 0: fp32; EPI 1: bf16; EPI 2: split N=384 -> two bf16 [*,192] buffers
template <int PERM, int ABF16, int EPI, int BM>
__global__ __launch_bounds__(256)
void gemm_mfma(const void* __restrict__ Ap, const ushortT* __restrict__ Bw,
               const float* __restrict__ bias, void* __restrict__ C1,
               void* __restrict__ C2, int M, int N, int K, int nbn) {
  __shared__ __align__(16) ushortT As[BM * 192];
  __shared__ __align__(16) ushortT Bs[64 * 192];
  int nwg = gridDim.x;
  int bid = blockIdx.x;
  int q = nwg >> 3, r = nwg & 7, xq = bid & 7, o = bid >> 3;
  int wg = (xq < r ? xq * (q + 1) : r * (q + 1) + (xq - r) * q) + o;
  int bn = (wg % nbn) * 64;
  int bm = (wg / nbn) * BM;
  int tid = threadIdx.x;
  int lane = tid & 63, w = tid >> 6;
  constexpr int MF = BM / 32;
  int wm = (w >> 1) * (MF * 16), wn = (w & 1) * 32;
  f32x4 acc[MF][2] = {};

  for (int k0 = 0; k0 < K; k0 += 192) {
    for (int ci = tid; ci < BM * 24; ci += 256) {
      int row = ci / 24, s = ci - row * 24;
      int srow = permrow<PERM>(bm + row);
      int sw = (s & ~7) | ((s ^ row) & 7);
      short8v v;
      if (ABF16) {
        v = *(const short8v*)((const ushortT*)Ap + (size_t)srow * K + k0 + s * 8);
      } else {
        const float* af = (const float*)Ap + (size_t)srow * K + k0 + s * 8;
        float4v f0 = *(const float4v*)af;
        float4v f1 = *(const float4v*)(af + 4);
#pragma unroll
        for (int j = 0; j < 4; ++j) v[j] = (short)f2bf(f0[j]);
#pragma unroll
        for (int j = 0; j < 4; ++j) v[4 + j] = (short)f2bf(f1[j]);
      }
      *(short8v*)&As[row * 192 + sw * 8] = v;
    }
    for (int ci = tid; ci < 64 * 24; ci += 256) {
      int row = ci / 24, s = ci - row * 24;
      int n = bn + row;
      int sw = (s & ~7) | ((s ^ row) & 7);
      short8v v = {};
      if (n < N) v = *(const short8v*)(Bw + (size_t)n * K + k0 + s * 8);
      *(short8v*)&Bs[row * 192 + sw * 8] = v;
    }
    __syncthreads();
#pragma unroll
    for (int kk = 0; kk < 6; ++kk) {
      int sbase = kk * 4 + (lane >> 4);
      bf16x8 a[MF], bfr[2];
#pragma unroll
      for (int mf = 0; mf < MF; ++mf) {
        int rw = wm + mf * 16 + (lane & 15);
        int sw = (sbase & ~7) | ((sbase ^ rw) & 7);
        a[mf] = __builtin_bit_cast(bf16x8, *(const short8v*)&As[rw * 192 + sw * 8]);
      }
#pragma unroll
      for (int nf = 0; nf < 2; ++nf) {
        int rw = wn + nf * 16 + (lane & 15);
        int sw = (sbase & ~7) | ((sbase ^ rw) & 7);
        bfr[nf] = __builtin_bit_cast(bf16x8, *(const short8v*)&Bs[rw * 192 + sw * 8]);
      }
#pragma unroll
      for (int mf = 0; mf < MF; ++mf)
#pragma unroll
        for (int nf = 0; nf < 2; ++nf)
          acc[mf][nf] = __builtin_amdgcn_mfma_f32_16x16x32_bf16(a[mf], bfr[nf], acc[mf][nf], 0, 0, 0);
    }
    __syncthreads();
  }
#pragma unroll
  for (int mf = 0; mf < MF; ++mf)
#pragma unroll
    for (int nf = 0; nf < 2; ++nf)
#pragma unroll
      for (int j = 0; j < 4; ++j) {
        int rowg = bm + wm + mf * 16 + ((lane >> 4) << 2) + j;
        int colg = bn + wn + nf * 16 + (lane & 15);
        if (colg < N) {
          float v2 = acc[mf][nf][j] + (bias ? bias[colg] : 0.f);
          if (EPI == 0)      ((float*)C1)[(size_t)rowg * N + colg] = v2;
          else if (EPI == 1) ((ushortT*)C1)[(size_t)rowg * N + colg] = f2bf(v2);
          else {
            if (colg < 192) ((ushortT*)C1)[(size_t)rowg * 192 + colg] = f2bf(v2);
            else            ((ushortT*)C2)[(size_t)rowg * 192 + colg - 192] = f2bf(v2);
          }
        }
      }
}

// ---------------- causal depthwise conv K=4 + silu (region, bf16 io, 8ch/thread) ----------------
__global__ void conv_region_k8(const ushortT* __restrict__ xs, const float* __restrict__ wt,
                               const float* __restrict__ cb, ushortT* __restrict__ out, int n8) {
  for (int i = blockIdx.x * blockDim.x + threadIdx.x; i < n8; i += gridDim.x * blockDim.x) {
    int cg = i % 24, row = i / 24;
    int c0 = cg * 8, l = row & 4095;
    float4v b0 = *(const float4v*)(cb + c0), b1 = *(const float4v*)(cb + c0 + 4);
    float acc[8] = {b0[0], b0[1], b0[2], b0[3], b1[0], b1[1], b1[2], b1[3]};
#pragma unroll
    for (int k = 0; k < 4; ++k) {
      int ls = l + k - 3;
      if (ls < 0) continue;
      short8v v = *(const short8v*)(xs + (size_t)(row + k - 3) * 192 + c0);
      float4v w0 = *(const float4v*)(wt + k * 192 + c0);
      float4v w1 = *(const float4v*)(wt + k * 192 + c0 + 4);
#pragma unroll
      for (int j = 0; j < 4; ++j) acc[j]     = fmaf(bf2f((ushortT)v[j]),     w0[j], acc[j]);
#pragma unroll
      for (int j = 0; j < 4; ++j) acc[4 + j] = fmaf(bf2f((ushortT)v[4 + j]), w1[j], acc[4 + j]);
    }
    short8v o;
#pragma unroll
    for (int j = 0; j < 8; ++j) o[j] = (short)f2bf(siluf_(acc[j]));
    *(short8v*)(out + (size_t)row * 192 + c0) = o;
  }
}

// ---------------- causal depthwise conv K=2 + silu (local, bf16 io, 8ch/thread) ----------------
__global__ void conv_local_k8(const ushortT* __restrict__ xs, const float* __restrict__ wt,
                              const float* __restrict__ cb, ushortT* __restrict__ out, int n8) {
  for (int i = blockIdx.x * blockDim.x + threadIdx.x; i < n8; i += gridDim.x * blockDim.x) {
    int cg = i % 24, row = i / 24;
    int c0 = cg * 8, t = row & 63;
    float4v b0 = *(const float4v*)(cb + c0), b1 = *(const float4v*)(cb + c0 + 4);
    float acc[8] = {b0[0], b0[1], b0[2], b0[3], b1[0], b1[1], b1[2], b1[3]};
    {
      short8v v = *(const short8v*)(xs + (size_t)row * 192 + c0);
      float4v w0 = *(const float4v*)(wt + 192 + c0);
      float4v w1 = *(const float4v*)(wt + 192 + c0 + 4);
#pragma unroll
      for (int j = 0; j < 4; ++j) acc[j]     = fmaf(bf2f((ushortT)v[j]),     w0[j], acc[j]);
#pragma unroll
      for (int j = 0; j < 4; ++j) acc[4 + j] = fmaf(bf2f((ushortT)v[4 + j]), w1[j], acc[4 + j]);
    }
    if (t > 0) {
      short8v v = *(const short8v*)(xs + (size_t)(row - 1) * 192 + c0);
      float4v w0 = *(const float4v*)(wt + c0);
      float4v w1 = *(const float4v*)(wt + c0 + 4);
#pragma unroll
      for (int j = 0; j < 4; ++j) acc[j]     = fmaf(bf2f((ushortT)v[j]),     w0[j], acc[j]);
#pragma unroll
      for (int j = 0; j < 4; ++j) acc[4 + j] = fmaf(bf2f((ushortT)v[4 + j]), w1[j], acc[4 + j]);
    }
    short8v o;
#pragma unroll
    for (int j = 0; j < 8; ++j) o[j] = (short)f2bf(siluf_(acc[j]));
    *(short8v*)(out + (size_t)row * 192 + c0) = o;
  }
}

// ======== region scan, chunked parallel: 128 chunks of 32, N=16 ========
__global__ __launch_bounds__(192)
void scanA_r(const ushortT* __restrict__ xc, const float* __restrict__ dbl,
             const float* __restrict__ dt_w, const float* __restrict__ dt_b,
             const float* __restrict__ Alog,
             float* __restrict__ Pc, float* __restrict__ Hc) {
  int blk = blockIdx.x;
  int chunk = blk & 127, seq = blk >> 7, dir = seq >> 2;
  int c = threadIdx.x;
  float A[16], P[16], H[16], wdt[12];
#pragma unroll
  for (int nn = 0; nn < 16; ++nn) {
    A[nn] = -__expf(Alog[(size_t)(dir * 192 + c) * 16 + nn]);
    P[nn] = 1.f; H[nn] = 0.f;
  }
#pragma unroll
  for (int r = 0; r < 12; ++r) wdt[r] = dt_w[(size_t)(dir * 12 + r) * 192 + c];
  float bdt = dt_b[dir * 192 + c];
  size_t rowbase = (size_t)seq * 4096 + chunk * 32;
  for (int t = 0; t < 32; ++t) {
    size_t row = rowbase + t;
    const float* dd = dbl + row * 44;
    float dtr = bdt;
#pragma unroll
    for (int r = 0; r < 12; ++r) dtr = fmaf(dd[r], wdt[r], dtr);
    float dtv = softplusf_(dtr);
    float dx = dtv * bf2f(xc[row * 192 + c]);
#pragma unroll
    for (int nn = 0; nn < 16; ++nn) {
      float a = __expf(dtv * A[nn]);
      P[nn] *= a;
      H[nn] = fmaf(a, H[nn], dx * dd[12 + nn]);
    }
  }
  size_t ob = ((size_t)(seq * 128 + chunk) * 192 + c) * 16;
#pragma unroll
  for (int nn = 0; nn < 16; ++nn) { Pc[ob + nn] = P[nn]; Hc[ob + nn] = H[nn]; }
}

__global__ __launch_bounds__(256)
void combine_r(float* __restrict__ Pc, const float* __restrict__ Hc) {
  int gid = blockIdx.x * 256 + threadIdx.x;
  int nn = gid & 15;
  int c = (gid >> 4) % 192;
  int seq = gid / (192 * 16);
  float h = 0.f;
  for (int ch = 0; ch < 128; ++ch) {
    size_t idx = (((size_t)(seq * 128 + ch) * 192 + c) << 4) + nn;
    float nh = fmaf(Pc[idx], h, Hc[idx]);
    Pc[idx] = h;
    h = nh;
  }
}

__global__ __launch_bounds__(192)
void scanC_r(const ushortT* __restrict__ xc, const float* __restrict__ dbl,
             ushortT* __restrict__ zg, const float* __restrict__ Pc,
             const float* __restrict__ dt_w, const float* __restrict__ dt_b,
             const float* __restrict__ Alog, const float* __restrict__ Dskip) {
  int blk = blockIdx.x;
  int chunk = blk & 127, seq = blk >> 7, dir = seq >> 2;
  int c = threadIdx.x;
  float A[16], h[16], wdt[12];
  size_t ob = ((size_t)(seq * 128 + chunk) * 192 + c) * 16;
#pragma unroll
  for (int nn = 0; nn < 16; ++nn) {
    A[nn] = -__expf(Alog[(size_t)(dir * 192 + c) * 16 + nn]);
    h[nn] = Pc[ob + nn];
  }
#pragma unroll
  for (int r = 0; r < 12; ++r) wdt[r] = dt_w[(size_t)(dir * 12 + r) * 192 + c];
  float bdt = dt_b[dir * 192 + c];
  float Dv  = Dskip[dir * 192 + c];
  size_t rowbase = (size_t)seq * 4096 + chunk * 32;
  for (int t = 0; t < 32; ++t) {
    size_t row = rowbase + t;
    const float* dd = dbl + row * 44;
    float dtr = bdt;
#pragma unroll
    for (int r = 0; r < 12; ++r) dtr = fmaf(dd[r], wdt[r], dtr);
    float dtv = softplusf_(dtr);
    float xv  = bf2f(xc[row * 192 + c]);
    float dx  = dtv * xv;
    float y = 0.f;
#pragma unroll
    for (int nn = 0; nn < 16; ++nn) {
      float a = __expf(dtv * A[nn]);
      h[nn] = fmaf(a, h[nn], dx * dd[12 + nn]);
      y = fmaf(h[nn], dd[28 + nn], y);
    }
    y = fmaf(xv, Dv, y);
    float zv = bf2f(zg[row * 192 + c]);
    zg[row * 192 + c] = f2bf(y * siluf_(zv));
  }
}

// ======== local scan, chunked: 256 windows, 4 chunks of 16, N=8 ========
__global__ __launch_bounds__(192)
void scanA_l(const ushortT* __restrict__ xc, const float* __restrict__ dbl,
             const float* __restrict__ dt_w, const float* __restrict__ dt_b,
             const float* __restrict__ Alog,
             float* __restrict__ Pc, float* __restrict__ Hc) {
  int blk = blockIdx.x;
  int chunk = blk & 3, win = blk >> 2;
  int c = threadIdx.x;
  float A[8], P[8], H[8], wdt[12];
#pragma unroll
  for (int nn = 0; nn < 8; ++nn) {
    A[nn] = -__expf(Alog[(size_t)c * 8 + nn]);
    P[nn] = 1.f; H[nn] = 0.f;
  }
#pragma unroll
  for (int r = 0; r < 12; ++r) wdt[r] = dt_w[(size_t)r * 192 + c];
  float bdt = dt_b[c];
  size_t rowbase = (size_t)win * 64 + chunk * 16;
  for (int t = 0; t < 16; ++t) {
    size_t row = rowbase + t;
    const float* dd = dbl + row * 28;
    float dtr = bdt;
#pragma unroll
    for (int r = 0; r < 12; ++r) dtr = fmaf(dd[r], wdt[r], dtr);
    float dtv = softplusf_(dtr);
    float dx = dtv * bf2f(xc[row * 192 + c]);
#pragma unroll
    for (int nn = 0; nn < 8; ++nn) {
      float a = __expf(dtv * A[nn]);
      P[nn] *= a;
      H[nn] = fmaf(a, H[nn], dx * dd[12 + nn]);
    }
  }
  size_t ob = ((size_t)(win * 4 + chunk) * 192 + c) * 8;
#pragma unroll
  for (int nn = 0; nn < 8; ++nn) { Pc[ob + nn] = P[nn]; Hc[ob + nn] = H[nn]; }
}

__global__ __launch_bounds__(256)
void combine_l(float* __restrict__ Pc, const float* __restrict__ Hc) {
  int gid = blockIdx.x * 256 + threadIdx.x;
  int nn = gid & 7;
  int c = (gid >> 3) % 192;
  int win = gid / (192 * 8);
  float h = 0.f;
#pragma unroll
  for (int ch = 0; ch < 4; ++ch) {
    size_t idx = (((size_t)(win * 4 + ch) * 192 + c) << 3) + nn;
    float nh = fmaf(Pc[idx], h, Hc[idx]);
    Pc[idx] = h;
    h = nh;
  }
}

__global__ __launch_bounds__(192)
void scanC_l(const ushortT* __restrict__ xc, const float* __restrict__ dbl,
             ushortT* __restrict__ zg, const float* __restrict__ Pc,
             const float* __restrict__ dt_w, const float* __restrict__ dt_b,
             const float* __restrict__ Alog, const float* __restrict__ Dskip) {
  int blk = blockIdx.x;
  int chunk = blk & 3, win = blk >> 2;
  int c = threadIdx.x;
  float A[8], h[8], wdt[12];
  size_t ob = ((size_t)(win * 4 + chunk) * 192 + c) * 8;
#pragma unroll
  for (int nn = 0; nn < 8; ++nn) {
    A[nn] = -__expf(Alog[(size_t)c * 8 + nn]);
    h[nn] = Pc[ob + nn];
  }
#pragma unroll
  for (int r = 0; r < 12; ++r) wdt[r] = dt_w[(size_t)r * 192 + c];
  float bdt = dt_b[c];
  float Dv  = Dskip[c];
  size_t rowbase = (size_t)win * 64 + chunk * 16;
  for (int t = 0; t < 16; ++t) {
    size_t row = rowbase + t;
    const float* dd = dbl + row * 28;
    float dtr = bdt;
#pragma unroll
    for (int r = 0; r < 12; ++r) dtr = fmaf(dd[r], wdt[r], dtr);
    float dtv = softplusf_(dtr);
    float xv  = bf2f(xc[row * 192 + c]);
    float dx  = dtv * xv;
    float y = 0.f;
#pragma unroll
    for (int nn = 0; nn < 8; ++nn) {
      float a = __expf(dtv * A[nn]);
      h[nn] = fmaf(a, h[nn], dx * dd[12 + nn]);
      y = fmaf(h[nn], dd[20 + nn], y);
    }
    y = fmaf(xv, Dv, y);
    float zv = bf2f(zg[row * 192 + c]);
    zg[row * 192 + c] = f2bf(y * siluf_(zv));
  }
}

// ---------------- combine 4 directional outputs (bf16 in, fp32 out, 8ch/thread) ----------------
__global__ void combine_k8(const ushortT* __restrict__ outr, const float* __restrict__ scale_mod,
                           float* __restrict__ reg, int n8) {
  const size_t BLC = (size_t)4 * 4096 * 192;
  float sc = 0.25f * scale_mod[0];
  for (int i = blockIdx.x * blockDim.x + threadIdx.x; i < n8; i += gridDim.x * blockDim.x) {
    int cg = i % 24, row = i / 24;
    int c0 = cg * 8, l = row & 4095, b = row >> 12;
    int hh = l >> 6, ww = l & 63;
    int lv = (ww << 6) | hh;
    size_t rb = (size_t)b * 4096;
    short8v v0 = *(const short8v*)(outr + ((rb + l) * 192) + c0);
    short8v v1 = *(const short8v*)(outr + BLC + ((rb + (4095 - l)) * 192) + c0);
    short8v v2 = *(const short8v*)(outr + 2 * BLC + ((rb + lv) * 192) + c0);
    short8v v3 = *(const short8v*)(outr + 3 * BLC + ((rb + (4095 - lv)) * 192) + c0);
    float4v o0, o1;
#pragma unroll
    for (int j = 0; j < 4; ++j)
      o0[j] = (bf2f((ushortT)v0[j]) + bf2f((ushortT)v1[j]) + bf2f((ushortT)v2[j]) + bf2f((ushortT)v3[j])) * sc;
#pragma unroll
    for (int j = 0; j < 4; ++j)
      o1[j] = (bf2f((ushortT)v0[4+j]) + bf2f((ushortT)v1[4+j]) + bf2f((ushortT)v2[4+j]) + bf2f((ushortT)v3[4+j])) * sc;
    *(float4v*)(reg + (size_t)row * 192 + c0) = o0;
    *(float4v*)(reg + (size_t)row * 192 + c0 + 4) = o1;
  }
}

// ---------------- fused += local out (un-window, bf16 in, 8ch/thread) ----------------
__global__ void fuse_k8(float* __restrict__ fused, const ushortT* __restrict__ outl, int n8) {
  for (int i = blockIdx.x * blockDim.x + threadIdx.x; i < n8; i += gridDim.x * blockDim.x) {
    int cg = i % 24, row = i / 24;
    int c0 = cg * 8, l = row & 4095, b = row >> 12;
    int hh = l >> 6, ww = l & 63;
    int win = ((b * 8 + (hh >> 3)) * 8) + (ww >> 3);
    int t = ((hh & 7) << 3) | (ww & 7);
    short8v v = *(const short8v*)(outl + ((size_t)win * 64 + t) * 192 + c0);
    float* fp = fused + (size_t)row * 192 + c0;
    float4v f0 = *(const float4v*)fp, f1 = *(const float4v*)(fp + 4);
#pragma unroll
    for (int j = 0; j < 4; ++j) f0[j] += bf2f((ushortT)v[j]);
#pragma unroll
    for (int j = 0; j < 4; ++j) f1[j] += bf2f((ushortT)v[4 + j]);
    *(float4v*)fp = f0;
    *(float4v*)(fp + 4) = f1;
  }
}

// ---------------- depthwise 3x3 + GLU: 8ch x 4row register tile, bf16 io ----------------
// grid: 1024 blocks x 192 thr. thread: grp=tid%48 (m0=grp*8), sub=tid/48 (x subcol)
__global__ __launch_bounds__(192)
void dwglu_k(const ushortT* __restrict__ h1, const float* __restrict__ dwt,
             const float* __restrict__ dw_b, ushortT* __restrict__ glu) {
  int tid = threadIdx.x;
  int grp = tid % 48, sub = tid / 48;
  int bx = blockIdx.x;
  int b = bx >> 8, xq = (bx >> 4) & 15, ys = bx & 15;
  int x = xq * 4 + sub, y0 = ys * 4;
  int m0 = grp * 8;
  float acc1[4][8], acc2[4][8];
  {
    float4v b1a = *(const float4v*)(dw_b + m0),       b1b = *(const float4v*)(dw_b + m0 + 4);
    float4v b2a = *(const float4v*)(dw_b + 384 + m0), b2b = *(const float4v*)(dw_b + 388 + m0);
#pragma unroll
    for (int iy = 0; iy < 4; ++iy)
#pragma unroll
      for (int j = 0; j < 4; ++j) {
        acc1[iy][j] = b1a[j]; acc1[iy][4 + j] = b1b[j];
        acc2[iy][j] = b2a[j]; acc2[iy][4 + j] = b2b[j];
      }
  }
#pragma unroll
  for (int dy = 0; dy < 3; ++dy) {
#pragma unroll
    for (int dx = 0; dx < 3; ++dx) {
      int xx = x + dx - 1;
      if (xx < 0 || xx >= 64) continue;
      int tap = dy * 3 + dx;
      float4v w1a = *(const float4v*)(dwt + tap * 768 + m0);
      float4v w1b = *(const float4v*)(dwt + tap * 768 + m0 + 4);
      float4v w2a = *(const float4v*)(dwt + tap * 768 + 384 + m0);
      float4v w2b = *(const float4v*)(dwt + tap * 768 + 388 + m0);
#pragma unroll
      for (int iy = 0; iy < 4; ++iy) {
        int yy = y0 + iy + dy - 1;
        if (yy < 0 || yy >= 64) continue;
        size_t pix = (size_t)(b * 4096) + yy * 64 + xx;
        short8v v1 = *(const short8v*)(h1 + pix * 768 + m0);
        short8v v2 = *(const short8v*)(h1 + pix * 768 + 384 + m0);
#pragma unroll
        for (int j = 0; j < 4; ++j) {
          acc1[iy][j]     = fmaf(bf2f((ushortT)v1[j]),     w1a[j], acc1[iy][j]);
          acc1[iy][4 + j] = fmaf(bf2f((ushortT)v1[4 + j]), w1b[j], acc1[iy][4 + j]);
          acc2[iy][j]     = fmaf(bf2f((ushortT)v2[j]),     w2a[j], acc2[iy][j]);
          acc2[iy][4 + j] = fmaf(bf2f((ushortT)v2[4 + j]), w2b[j], acc2[iy][4 + j]);
        }
      }
    }
  }
#pragma unroll
  for (int iy = 0; iy < 4; ++iy) {
    size_t pix = (size_t)(b * 4096) + (y0 + iy) * 64 + x;
    short8v o;
#pragma unroll
    for (int j = 0; j < 8; ++j) o[j] = (short)f2bf(acc1[iy][j] * sigmoidf_(acc2[iy][j]));
    *(short8v*)(glu + pix * 384 + m0) = o;
  }
}

// ---------------- final: out = x + gamma*(fused + sgout), NHWC->NCHW via LDS ----------------
__global__ __launch_bounds__(256)
void final_k_t(const float* __restrict__ x, const float* __restrict__ fused,
               const float* __restrict__ sgout, const float* __restrict__ gamma,
               float* __restrict__ out) {
  __shared__ float tile[192][65];
  float gm = gamma[0];
  int bb = blockIdx.x >> 6;
  int p0 = (blockIdx.x & 63) << 6;
  int tid = threadIdx.x;
  for (int e = tid; e < 64 * 192; e += 256) {
    int pp = e / 192, c = e % 192;
    size_t idx = ((size_t)(bb * 4096) + p0 + pp) * 192 + c;
    tile[c][pp] = gm * (fused[idx] + sgout[idx]);
  }
  __syncthreads();
  for (int e = tid; e < 192 * 64; e += 256) {
    int c = e / 64, p = e % 64;
    size_t oi = ((size_t)(bb * 192 + c)) * 4096 + p0 + p;
    out[oi] = x[oi] + tile[c][p];
  }
}

extern "C" void kernel_launch(void* const* d_in, const int* in_sizes, int n_in,
                              void* d_out, int out_size, void* d_ws, size_t ws_size,
                              hipStream_t stream) {
  const float* x         = (const float*)d_in[0];
  const float* r_conv_w  = (const float*)d_in[2];
  const float* r_conv_b  = (const float*)d_in[3];
  const float* r_dt_w    = (const float*)d_in[5];
  const float* r_dt_b    = (const float*)d_in[6];
  const float* r_Alog    = (const float*)d_in[7];
  const float* r_D       = (const float*)d_in[8];
  const float* scale_mod = (const float*)d_in[10];
  const float* l_conv_w  = (const float*)d_in[12];
  const float* l_conv_b  = (const float*)d_in[13];
  const float* l_dt_w    = (const float*)d_in[15];
  const float* l_dt_b    = (const float*)d_in[16];
  const float* l_Alog    = (const float*)d_in[17];
  const float* l_D       = (const float*)d_in[18];
  const float* ln_g      = (const float*)d_in[20];
  const float* ln_b      = (const float*)d_in[21];
  const float* c1_b      = (const float*)d_in[23];
  const float* dw_w      = (const float*)d_in[24];
  const float* dw_b      = (const float*)d_in[25];
  const float* c2_b      = (const float*)d_in[27];
  const float* gamma     = (const float*)d_in[28];
  float* out = (float*)d_out;

  // ---- workspace arena ----
  float* W = (float*)d_ws;
  const size_t BLC = (size_t)4 * 4096 * 192;
  float*   xn    = W;                                  // [16384][192] fp32
  ushortT* xcbf  = (ushortT*)(W + BLC);                // 4*BLC bf16 (xc per dir; local xc)
  ushortT* outr  = xcbf;                               // bf16 outr/outl (after xc dead)
  ushortT* zbf   = (ushortT*)(W + 3 * BLC);            // 4*BLC bf16 (z -> g)
  ushortT* xsbf  = (ushortT*)(W + 5 * BLC);            // BLC bf16 (conv input, transient)
  float*   dbl   = W + 5 * BLC + BLC / 2;              // region 4*720896; local 458752 fp32
  float*   Pc    = W + 5 * BLC + BLC / 2 + 2883584;    // 6,291,456 fp32
  float*   Hc    = Pc + 6291456;                       // 6,291,456 fp32
  float*   fused = Pc;                                 // BLC fp32
  float*   Pl    = Hc;
  float*   Hl    = Hc + 1572864;
  ushortT* h1    = (ushortT*)W;                        // [16384][768] bf16 (SGFN)
  ushortT* glu   = (ushortT*)(W + 4 * BLC);            // [16384][384] bf16
  float*   sgout = Hc;                                 // BLC fp32
  ushortT* wbf   = (ushortT*)(Hc + 6291456);           // 813,312 bf16 weights
  float*   cwt   = Hc + 6291456 + 406656;              // 10,368 fp32 (dwt|rcwt|lcwt)

  auto gs = [](size_t n) { size_t g = (n + 255) / 256; return (int)(g > 8192 ? 8192 : g); };
  const int nBLC8 = (int)(BLC / 8);

  // 0. weight prep
  prep_w<<<(813312 + 255) / 256, 256, 0, stream>>>((const float*)d_in[1], (const float*)d_in[4],
                                                   (const float*)d_in[9], (const float*)d_in[11],
                                                   (const float*)d_in[14], (const float*)d_in[19],
                                                   (const float*)d_in[22], (const float*)d_in[26], wbf);
  prep_cw<<<41, 256, 0, stream>>>(dw_w, r_conv_w, l_conv_w, cwt);
  const float* dwt  = cwt;
  const float* rcwt = cwt + 6912;
  const float* lcwt = cwt + 9984;

  // 1. LayerNorm
  ln_kernel<<<dim3(256), dim3(256), 0, stream>>>(x, ln_g, ln_b, xn);

  // 2. Region branch
  const ushortT* w_in  = wbf;            // [384][192] x4
  const ushortT* w_xp  = wbf + 294912;   // [44][192]  x4
  const ushortT* w_out = wbf + 328704;   // [192][192] x4
  for (int d = 0; d < 4; ++d) {
    const ushortT* wi = w_in + (size_t)d * 73728;
    ushortT* zd = zbf + (size_t)d * BLC;
    switch (d) {   // merged xs+z GEMM, N=384, split epilogue
      case 0: gemm_mfma<0,0,2,64><<<1536, 256, 0, stream>>>(xn, wi, nullptr, xsbf, zd, 16384, 384, 192, 6); break;
      case 1: gemm_mfma<1,0,2,64><<<1536, 256, 0, stream>>>(xn, wi, nullptr, xsbf, zd, 16384, 384, 192, 6); break;
      case 2: gemm_mfma<2,0,2,64><<<1536, 256, 0, stream>>>(xn, wi, nullptr, xsbf, zd, 16384, 384, 192, 6); break;
      case 3: gemm_mfma<3,0,2,64><<<1536, 256, 0, stream>>>(xn, wi, nullptr, xsbf, zd, 16384, 384, 192, 6); break;
    }
    conv_region_k8<<<gs(BLC / 8), 256, 0, stream>>>(xsbf, rcwt + (size_t)d * 768,
                                                    r_conv_b + (size_t)d * 192,
                                                    xcbf + (size_t)d * BLC, nBLC8);
    gemm_mfma<0,1,0,64><<<256, 256, 0, stream>>>(xcbf + (size_t)d * BLC, w_xp + (size_t)d * 8448,
                                                 nullptr, dbl + (size_t)d * 720896, nullptr,
                                                 16384, 44, 192, 1);
  }
  scanA_r<<<2048, 192, 0, stream>>>(xcbf, dbl, r_dt_w, r_dt_b, r_Alog, Pc, Hc);
  combine_r<<<192, 256, 0, stream>>>(Pc, Hc);
  scanC_r<<<2048, 192, 0, stream>>>(xcbf, dbl, zbf, Pc, r_dt_w, r_dt_b, r_Alog, r_D);
  for (int d = 0; d < 4; ++d)
    gemm_mfma<0,1,1,64><<<768, 256, 0, stream>>>(zbf + (size_t)d * BLC, w_out + (size_t)d * 36864,
                                                 nullptr, outr + (size_t)d * BLC, nullptr,
                                                 16384, 192, 192, 3);
  combine_k8<<<gs(BLC / 8), 256, 0, stream>>>(outr, scale_mod, fused, nBLC8);

  // 3. Local windowed branch
  const ushortT* wl_in  = wbf + 476160;
  const ushortT* wl_xp  = wbf + 549888;
  const ushortT* wl_out = wbf + 555264;
  gemm_mfma<4,0,2,64><<<1536, 256, 0, stream>>>(xn, wl_in, nullptr, xsbf, zbf, 16384, 384, 192, 6);
  conv_local_k8<<<gs(BLC / 8), 256, 0, stream>>>(xsbf, lcwt, l_conv_b, xcbf, nBLC8);
  gemm_mfma<0,1,0,64><<<256, 256, 0, stream>>>(xcbf, wl_xp, nullptr, dbl, nullptr, 16384, 28, 192, 1);
  scanA_l<<<1024, 192, 0, stream>>>(xcbf, dbl, l_dt_w, l_dt_b, l_Alog, Pl, Hl);
  combine_l<<<1536, 256, 0, stream>>>(Pl, Hl);
  scanC_l<<<1024, 192, 0, stream>>>(xcbf, dbl, zbf, Pl, l_dt_w, l_dt_b, l_Alog, l_D);
  gemm_mfma<0,1,1,64><<<768, 256, 0, stream>>>(zbf, wl_out, nullptr, outr, nullptr, 16384, 192, 192, 3);
  fuse_k8<<<gs(BLC / 8), 256, 0, stream>>>(fused, outr, nBLC8);

  // 4. SGFN + final residual
  const ushortT* w_c1 = wbf + 592128;
  const ushortT* w_c2 = wbf + 739584;
  gemm_mfma<0,0,1,128><<<1536, 256, 0, stream>>>(fused, w_c1, c1_b, h1, nullptr, 16384, 768, 192, 12);
  dwglu_k<<<1024, 192, 0, stream>>>(h1, dwt, dw_b, glu);
  gemm_mfma<0,1,0,128><<<384, 256, 0, stream>>>(glu, w_c2, c2_b, sgout, nullptr, 16384, 192, 384, 3);
  final_k_t<<<256, 256, 0, stream>>>(x, fused, sgout, gamma, out);
}